// Round 8
// baseline (390.686 us; speedup 1.0000x reference)
//
#include <hip/hip_runtime.h>
#include <hip/hip_bf16.h>
#include <math.h>

#define NN 40000
#define NE 640000

typedef __attribute__((ext_vector_type(8))) short short8;
typedef __attribute__((ext_vector_type(8))) unsigned short u16x8;
typedef __attribute__((ext_vector_type(4))) float f32x4;

#define WBLOCKS 547   // weight-prep blocks (547*256 = 140032 = exactly the prep items)
#define HBLOCKS 2500  // hist blocks

__device__ __forceinline__ float gelu_tanh(float x) {
    float x3 = x * x * x;
    float u = 0.7978845608028654f * (x + 0.044715f * x3);
    return 0.5f * x * (1.0f + tanhf(u));
}

__device__ __forceinline__ unsigned short f2bf(float v) {
    __hip_bfloat16 h = __float2bfloat16(v);
    return *reinterpret_cast<unsigned short*>(&h);
}

__device__ __forceinline__ float bf2f(unsigned short u) {
    union { unsigned int i; float f; } c;
    c.i = ((unsigned int)u) << 16;
    return c.f;
}

__device__ __forceinline__ void unpack8(u16x8 u, float* f) {
    union { u16x8 v; unsigned int d[4]; } c; c.v = u;
    #pragma unroll
    for (int i = 0; i < 4; ++i) {
        union { unsigned int i_; float f_; } lo, hi;
        lo.i_ = c.d[i] << 16;
        hi.i_ = c.d[i] & 0xffff0000u;
        f[2 * i] = lo.f_;
        f[2 * i + 1] = hi.f_;
    }
}

// ---------------- prep: weights (blocks 0..546) + degree histogram (blocks 547..) ----
// BfT[l][384][128] bf16, biasf[l][384] f32, aWT[l][128][128] bf16, fcWT[64][128] bf16
// k-section folds p_rel * 0.25 * log2(e)
__global__ __launch_bounds__(256) void prep_kernel(
    const float* __restrict__ Wq, const float* __restrict__ bq,
    const float* __restrict__ Wk, const float* __restrict__ bk,
    const float* __restrict__ a_rel,
    const float* __restrict__ Wv, const float* __restrict__ bv,
    const float* __restrict__ m_rel,
    const float* __restrict__ p_rel,
    const float* __restrict__ aW, const float* __restrict__ fcW,
    unsigned short* __restrict__ BfT, float* __restrict__ biasf,
    unsigned short* __restrict__ aWT, unsigned short* __restrict__ fcWT,
    const int* __restrict__ eidx, int* __restrict__ deg)
{
    if (blockIdx.x >= WBLOCKS) {
        int e = (blockIdx.x - WBLOCKS) * 256 + threadIdx.x;
        if (e < NE) atomicAdd(&deg[eidx[NE + e]], 1);
        return;
    }
    int idx = blockIdx.x * 256 + threadIdx.x;
    if (idx < 2 * 129 * 384) {
        int l = idx / (129 * 384);
        int j = idx - l * (129 * 384);
        int r = j / 384;
        int col = j - r * 384;
        const float* Wq_l = Wq + l * 16384;
        const float* Wk_l = Wk + l * 16384;
        const float* Wv_l = Wv + l * 16384;
        const float* ar_l = a_rel + l * 2048;
        const float* mr_l = m_rel + l * 2048;
        float val;
        if (col < 128) {
            val = (r < 128) ? Wq_l[r * 128 + col] : bq[l * 128 + col];
        } else if (col < 256) {
            int cc = col - 128; int h = cc >> 4; int eo = cc & 15;
            float scale = p_rel[l * 8 + h] * 0.25f * 1.4426950408889634f;
            float s = 0.f;
            #pragma unroll
            for (int d = 0; d < 16; ++d) {
                float w = (r < 128) ? Wk_l[r * 128 + h * 16 + d] : bk[l * 128 + h * 16 + d];
                s += w * ar_l[h * 256 + d * 16 + eo];
            }
            val = s * scale;
        } else {
            int cc = col - 256; int h = cc >> 4; int eo = cc & 15;
            float s = 0.f;
            #pragma unroll
            for (int d = 0; d < 16; ++d) {
                float w = (r < 128) ? Wv_l[r * 128 + h * 16 + d] : bv[l * 128 + h * 16 + d];
                s += w * mr_l[h * 256 + d * 16 + eo];
            }
            val = s;
        }
        if (r < 128) BfT[(size_t)l * 49152 + (size_t)col * 128 + r] = f2bf(val);
        else         biasf[l * 384 + col] = val;
    } else if (idx < 2 * 129 * 384 + 2 * 16384) {
        int i = idx - 2 * 129 * 384;
        int l = i >> 14; int j = i & 16383;
        int r = j >> 7, c = j & 127;
        aWT[(size_t)l * 16384 + (size_t)c * 128 + r] = f2bf(aW[(size_t)l * 16384 + r * 128 + c]);
    } else {
        int i = idx - (2 * 129 * 384 + 2 * 16384);
        int c = i >> 7, r = i & 127;
        fcWT[(size_t)c * 128 + r] = f2bf(fcW[(size_t)r * 64 + c]);
    }
}

// ---------------- single-block scan: deg -> exclusive offs (+cursor copy) --------
__global__ __launch_bounds__(1024) void scan_kernel(
    const int* __restrict__ deg, int* __restrict__ offs, int* __restrict__ cursor)
{
    __shared__ int s[1024];
    int t = threadIdx.x;
    const int CH = 40;           // 1024*40 >= 40000
    int base = t * CH;
    int loc[CH];
    int sum = 0;
    #pragma unroll
    for (int j = 0; j < CH; ++j) {
        int i = base + j;
        int v = (i < NN) ? deg[i] : 0;
        loc[j] = sum;
        sum += v;
    }
    s[t] = sum;
    __syncthreads();
    for (int off = 1; off < 1024; off <<= 1) {
        int u = (t >= off) ? s[t - off] : 0;
        __syncthreads();
        s[t] += u;
        __syncthreads();
    }
    int prefix = s[t] - sum;
    #pragma unroll
    for (int j = 0; j < CH; ++j) {
        int i = base + j;
        if (i < NN) {
            int o = prefix + loc[j];
            offs[i] = o;
            cursor[i] = o;
        }
    }
}

__global__ __launch_bounds__(256) void scatter_kernel(
    const int* __restrict__ eidx, int* __restrict__ cursor, int* __restrict__ srcSorted)
{
    int e = blockIdx.x * 256 + threadIdx.x;
    if (e < NE) {
        int s = eidx[e];
        int d = eidx[NE + e];
        int pos = atomicAdd(&cursor[d], 1);
        srcSorted[pos] = s;
    }
}

// ---- GEMM helpers: swapped-operand MFMA (lane owns one C row, 4-col frags) ----
// kvb layout: per node row of 256 ushorts = [k(128) | v(128)], 512 B contiguous.

__global__ __launch_bounds__(256) void qkv0_kernel(
    const float* __restrict__ Af, const unsigned short* __restrict__ BT,
    const float* __restrict__ bias,
    unsigned short* __restrict__ qb, unsigned short* __restrict__ kvb)
{
    __shared__ unsigned short As[64][136];
    __shared__ unsigned short Bs[64][136];
    int t = threadIdx.x;
    int row0 = blockIdx.x * 64;
    int w = t >> 6;
    int lr = t & 15;
    int quad = (t & 63) >> 4;

    #pragma unroll
    for (int i = 0; i < 4; ++i) {
        int idx = t + i * 256;
        int r = idx >> 4;
        int c8 = (idx & 15) * 8;
        float4 a0 = *(const float4*)(Af + (size_t)(row0 + r) * 128 + c8);
        float4 a1 = *(const float4*)(Af + (size_t)(row0 + r) * 128 + c8 + 4);
        ushort4 u0, u1;
        u0.x = f2bf(a0.x); u0.y = f2bf(a0.y); u0.z = f2bf(a0.z); u0.w = f2bf(a0.w);
        u1.x = f2bf(a1.x); u1.y = f2bf(a1.y); u1.z = f2bf(a1.z); u1.w = f2bf(a1.w);
        *(ushort4*)(&As[r][c8]) = u0;
        *(ushort4*)(&As[r][c8 + 4]) = u1;
    }

    int row = row0 + w * 16 + lr;
    #pragma unroll
    for (int ct = 0; ct < 6; ++ct) {
        __syncthreads();
        #pragma unroll
        for (int i = 0; i < 4; ++i) {
            int idx = t + i * 256;
            int r = idx >> 4;
            int c8 = (idx & 15) * 8;
            *(u16x8*)(&Bs[r][c8]) = *(const u16x8*)(BT + (size_t)(ct * 64 + r) * 128 + c8);
        }
        __syncthreads();
        f32x4 acc[4] = {{0.f,0.f,0.f,0.f},{0.f,0.f,0.f,0.f},
                        {0.f,0.f,0.f,0.f},{0.f,0.f,0.f,0.f}};
        #pragma unroll
        for (int kc = 0; kc < 4; ++kc) {
            short8 af = *(const short8*)(&As[w * 16 + lr][kc * 32 + quad * 8]);
            #pragma unroll
            for (int n4 = 0; n4 < 4; ++n4) {
                short8 bfr = *(const short8*)(&Bs[n4 * 16 + lr][kc * 32 + quad * 8]);
                acc[n4] = __builtin_amdgcn_mfma_f32_16x16x32_bf16(bfr, af, acc[n4], 0, 0, 0);
            }
        }
        unsigned short* dst = (ct < 2) ? (qb + (size_t)row * 128 + (ct & 1) * 64)
                                       : (kvb + (size_t)row * 256 + (ct - 2) * 64);
        #pragma unroll
        for (int n4 = 0; n4 < 4; ++n4) {
            int colb = n4 * 16 + quad * 4;
            float4 bv = *(const float4*)(bias + ct * 64 + colb);
            ushort4 o;
            o.x = f2bf(acc[n4][0] + bv.x);
            o.y = f2bf(acc[n4][1] + bv.y);
            o.z = f2bf(acc[n4][2] + bv.z);
            o.w = f2bf(acc[n4][3] + bv.w);
            *(ushort4*)(dst + colb) = o;
        }
    }
}

// Fused: out-GEMM (gelu(agg)@aWT + skip -> h) then second GEMM from h (in LDS).
// HPFMT: 0 = Hprev f32, 1 = Hprev bf16.  P2: 0 = QKV out (store hb too), 2 = fc f32 out.
template <int HPFMT, int P2>
__global__ __launch_bounds__(256) void fused_kernel(
    const unsigned short* __restrict__ aggb,
    const unsigned short* __restrict__ aWT, const float* __restrict__ ab,
    const float* __restrict__ skip_p,
    const float* __restrict__ HprevF, const unsigned short* __restrict__ HprevB,
    unsigned short* __restrict__ hb_out,
    const unsigned short* __restrict__ W2T, const float* __restrict__ bias2,
    unsigned short* __restrict__ qb, unsigned short* __restrict__ kvb,
    float* __restrict__ outF)
{
    __shared__ unsigned short As[64][136];
    __shared__ unsigned short Bs[64][136];
    int t = threadIdx.x;
    int row0 = blockIdx.x * 64;
    int w = t >> 6;
    int lr = t & 15;
    int quad = (t & 63) >> 4;

    #pragma unroll
    for (int i = 0; i < 4; ++i) {
        int idx = t + i * 256;
        int r = idx >> 4;
        int c8 = (idx & 15) * 8;
        u16x8 u = *(const u16x8*)(aggb + (size_t)(row0 + r) * 128 + c8);
        #pragma unroll
        for (int j = 0; j < 8; ++j) u[j] = f2bf(gelu_tanh(bf2f(u[j])));
        *(u16x8*)(&As[r][c8]) = u;
    }

    float sv = skip_p[0];
    float beta = 1.f / (1.f + expf(-sv));
    float omb = 1.f - beta;
    int row = row0 + w * 16 + lr;

    f32x4 hacc[2][4];
    #pragma unroll
    for (int ct = 0; ct < 2; ++ct) {
        __syncthreads();
        #pragma unroll
        for (int i = 0; i < 4; ++i) {
            int idx = t + i * 256;
            int r = idx >> 4;
            int c8 = (idx & 15) * 8;
            *(u16x8*)(&Bs[r][c8]) = *(const u16x8*)(aWT + (size_t)(ct * 64 + r) * 128 + c8);
        }
        __syncthreads();
        #pragma unroll
        for (int n4 = 0; n4 < 4; ++n4) hacc[ct][n4] = (f32x4){0.f,0.f,0.f,0.f};
        #pragma unroll
        for (int kc = 0; kc < 4; ++kc) {
            short8 af = *(const short8*)(&As[w * 16 + lr][kc * 32 + quad * 8]);
            #pragma unroll
            for (int n4 = 0; n4 < 4; ++n4) {
                short8 bfr = *(const short8*)(&Bs[n4 * 16 + lr][kc * 32 + quad * 8]);
                hacc[ct][n4] = __builtin_amdgcn_mfma_f32_16x16x32_bf16(bfr, af, hacc[ct][n4], 0, 0, 0);
            }
        }
    }
    __syncthreads();

    #pragma unroll
    for (int ct = 0; ct < 2; ++ct) {
        #pragma unroll
        for (int n4 = 0; n4 < 4; ++n4) {
            int colb = ct * 64 + n4 * 16 + quad * 4;
            float4 bv = *(const float4*)(ab + colb);
            float hp[4];
            if (HPFMT == 0) {
                float4 h4 = *(const float4*)(HprevF + (size_t)row * 128 + colb);
                hp[0] = h4.x; hp[1] = h4.y; hp[2] = h4.z; hp[3] = h4.w;
            } else {
                ushort4 h4 = *(const ushort4*)(HprevB + (size_t)row * 128 + colb);
                hp[0] = bf2f(h4.x); hp[1] = bf2f(h4.y); hp[2] = bf2f(h4.z); hp[3] = bf2f(h4.w);
            }
            ushort4 o;
            o.x = f2bf(fmaxf(beta * (hacc[ct][n4][0] + bv.x) + omb * hp[0], 0.f));
            o.y = f2bf(fmaxf(beta * (hacc[ct][n4][1] + bv.y) + omb * hp[1], 0.f));
            o.z = f2bf(fmaxf(beta * (hacc[ct][n4][2] + bv.z) + omb * hp[2], 0.f));
            o.w = f2bf(fmaxf(beta * (hacc[ct][n4][3] + bv.w) + omb * hp[3], 0.f));
            *(ushort4*)(&As[w * 16 + lr][colb]) = o;
            if (P2 == 0) *(ushort4*)(hb_out + (size_t)row * 128 + colb) = o;
        }
    }
    __syncthreads();

    if (P2 == 0) {
        #pragma unroll
        for (int ct = 0; ct < 6; ++ct) {
            if (ct) __syncthreads();
            #pragma unroll
            for (int i = 0; i < 4; ++i) {
                int idx = t + i * 256;
                int r = idx >> 4;
                int c8 = (idx & 15) * 8;
                *(u16x8*)(&Bs[r][c8]) = *(const u16x8*)(W2T + (size_t)(ct * 64 + r) * 128 + c8);
            }
            __syncthreads();
            f32x4 acc[4] = {{0.f,0.f,0.f,0.f},{0.f,0.f,0.f,0.f},
                            {0.f,0.f,0.f,0.f},{0.f,0.f,0.f,0.f}};
            #pragma unroll
            for (int kc = 0; kc < 4; ++kc) {
                short8 af = *(const short8*)(&As[w * 16 + lr][kc * 32 + quad * 8]);
                #pragma unroll
                for (int n4 = 0; n4 < 4; ++n4) {
                    short8 bfr = *(const short8*)(&Bs[n4 * 16 + lr][kc * 32 + quad * 8]);
                    acc[n4] = __builtin_amdgcn_mfma_f32_16x16x32_bf16(bfr, af, acc[n4], 0, 0, 0);
                }
            }
            unsigned short* dst = (ct < 2) ? (qb + (size_t)row * 128 + (ct & 1) * 64)
                                           : (kvb + (size_t)row * 256 + (ct - 2) * 64);
            #pragma unroll
            for (int n4 = 0; n4 < 4; ++n4) {
                int colb = n4 * 16 + quad * 4;
                float4 bv = *(const float4*)(bias2 + ct * 64 + colb);
                ushort4 o;
                o.x = f2bf(acc[n4][0] + bv.x);
                o.y = f2bf(acc[n4][1] + bv.y);
                o.z = f2bf(acc[n4][2] + bv.z);
                o.w = f2bf(acc[n4][3] + bv.w);
                *(ushort4*)(dst + colb) = o;
            }
        }
    } else {
        #pragma unroll
        for (int i = 0; i < 4; ++i) {
            int idx = t + i * 256;
            int r = idx >> 4;
            int c8 = (idx & 15) * 8;
            *(u16x8*)(&Bs[r][c8]) = *(const u16x8*)(W2T + (size_t)r * 128 + c8);
        }
        __syncthreads();
        f32x4 acc[4] = {{0.f,0.f,0.f,0.f},{0.f,0.f,0.f,0.f},
                        {0.f,0.f,0.f,0.f},{0.f,0.f,0.f,0.f}};
        #pragma unroll
        for (int kc = 0; kc < 4; ++kc) {
            short8 af = *(const short8*)(&As[w * 16 + lr][kc * 32 + quad * 8]);
            #pragma unroll
            for (int n4 = 0; n4 < 4; ++n4) {
                short8 bfr = *(const short8*)(&Bs[n4 * 16 + lr][kc * 32 + quad * 8]);
                acc[n4] = __builtin_amdgcn_mfma_f32_16x16x32_bf16(bfr, af, acc[n4], 0, 0, 0);
            }
        }
        #pragma unroll
        for (int n4 = 0; n4 < 4; ++n4) {
            int colb = n4 * 16 + quad * 4;
            float4 bv = *(const float4*)(bias2 + colb);
            float4 o;
            o.x = acc[n4][0] + bv.x;
            o.y = acc[n4][1] + bv.y;
            o.z = acc[n4][2] + bv.z;
            o.w = acc[n4][3] + bv.w;
            *(float4*)(outF + (size_t)row * 64 + colb) = o;
        }
    }
}

// ---------------- Fused per-destination softmax + aggregation --------------------
// One wave per dst. lane = es*8 + h. kvb row = [k(128)|v(128)] bf16, 512 B.
// Depth-2 register prefetch: 3 generations, 24 outstanding loads per wave.
__global__ __launch_bounds__(256) void aggregate_kernel(
    const unsigned short* __restrict__ qb, const unsigned short* __restrict__ kvb,
    const int* __restrict__ deg, const int* __restrict__ offs,
    const int* __restrict__ srcSorted, unsigned short* __restrict__ aggb)
{
    int n = (blockIdx.x * 256 + threadIdx.x) >> 6;
    int lane = threadIdx.x & 63;
    int es = lane >> 3;
    int h = lane & 7;

    float q[16];
    {
        const unsigned short* qp = qb + (size_t)n * 128 + h * 16;
        unpack8(*(const u16x8*)qp, q);
        unpack8(*(const u16x8*)(qp + 8), q + 8);
    }
    float acc[16];
    #pragma unroll
    for (int j = 0; j < 16; ++j) acc[j] = 0.f;
    float den = 0.f;

    int start = offs[n];
    int d = deg[n];
    if (d > 0) {
        int ng = (d + 7) >> 3;
        int lastIdx = start + d - 1;

        u16x8 ka0, ka1, vA0, vA1, kB0, kB1, vB0, vB1;
        {
            int i0 = start + es; if (i0 > lastIdx) i0 = lastIdx;
            const unsigned short* p = kvb + (size_t)srcSorted[i0] * 256 + h * 16;
            ka0 = *(const u16x8*)p;        ka1 = *(const u16x8*)(p + 8);
            vA0 = *(const u16x8*)(p + 128); vA1 = *(const u16x8*)(p + 136);
        }
        kB0 = ka0; kB1 = ka1; vB0 = vA0; vB1 = vA1;
        if (ng > 1) {
            int i1 = start + 8 + es; if (i1 > lastIdx) i1 = lastIdx;
            const unsigned short* p = kvb + (size_t)srcSorted[i1] * 256 + h * 16;
            kB0 = *(const u16x8*)p;        kB1 = *(const u16x8*)(p + 8);
            vB0 = *(const u16x8*)(p + 128); vB1 = *(const u16x8*)(p + 136);
        }

        for (int g = 0; g < ng; ++g) {
            u16x8 kC0 = ka0, kC1 = ka1, vC0 = vA0, vC1 = vA1;
            if (g + 2 < ng) {
                int ni = start + (g + 2) * 8 + es; if (ni > lastIdx) ni = lastIdx;
                const unsigned short* p = kvb + (size_t)srcSorted[ni] * 256 + h * 16;
                kC0 = *(const u16x8*)p;        kC1 = *(const u16x8*)(p + 8);
                vC0 = *(const u16x8*)(p + 128); vC1 = *(const u16x8*)(p + 136);
            }
            float kf[16];
            unpack8(ka0, kf); unpack8(ka1, kf + 8);
            float p = 0.f;
            #pragma unroll
            for (int j = 0; j < 16; ++j) p = fmaf(q[j], kf[j], p);
            float ev = (g * 8 + es < d) ? exp2f(p) : 0.f;
            den += ev;
            float vf[16];
            unpack8(vA0, vf); unpack8(vA1, vf + 8);
            #pragma unroll
            for (int j = 0; j < 16; ++j) acc[j] = fmaf(vf[j], ev, acc[j]);
            ka0 = kB0; ka1 = kB1; vA0 = vB0; vA1 = vB1;
            kB0 = kC0; kB1 = kC1; vB0 = vC0; vB1 = vC1;
        }
    }
    #pragma unroll
    for (int m = 8; m < 64; m <<= 1) {
        den += __shfl_xor(den, m, 64);
        #pragma unroll
        for (int j = 0; j < 16; ++j) acc[j] += __shfl_xor(acc[j], m, 64);
    }
    if (es == 0) {
        float w = 1.f / (den + 1e-16f);
        u16x8 o0, o1;
        #pragma unroll
        for (int j = 0; j < 8; ++j) {
            o0[j] = f2bf(acc[j] * w);
            o1[j] = f2bf(acc[j + 8] * w);
        }
        *(u16x8*)(aggb + (size_t)n * 128 + h * 16) = o0;
        *(u16x8*)(aggb + (size_t)n * 128 + h * 16 + 8) = o1;
    }
}

extern "C" void kernel_launch(void* const* d_in, const int* in_sizes, int n_in,
                              void* d_out, int out_size, void* d_ws, size_t ws_size,
                              hipStream_t stream) {
    const float* x     = (const float*)d_in[0];
    const int*   eidx  = (const int*)d_in[1];
    const float* Wk    = (const float*)d_in[2];
    const float* bk    = (const float*)d_in[3];
    const float* Wq    = (const float*)d_in[4];
    const float* bq    = (const float*)d_in[5];
    const float* Wv    = (const float*)d_in[6];
    const float* bv    = (const float*)d_in[7];
    const float* a_rel = (const float*)d_in[8];
    const float* m_rel = (const float*)d_in[9];
    const float* p_rel = (const float*)d_in[10];
    const float* skip  = (const float*)d_in[11];
    const float* aW    = (const float*)d_in[12];
    const float* ab    = (const float*)d_in[13];
    const float* fcW   = (const float*)d_in[14];
    const float* fcb   = (const float*)d_in[15];
    float* out = (float*)d_out;

    float* biasf = (float*)d_ws;                              // 2*384
    unsigned short* hb   = (unsigned short*)(biasf + 768);    // NN*128
    unsigned short* qb   = hb + (size_t)NN * 128;             // NN*128
    unsigned short* kvb  = qb + (size_t)NN * 128;             // NN*256 ([k|v] rows)
    unsigned short* aggb = kvb + (size_t)NN * 256;            // NN*128
    unsigned short* BfT  = aggb + (size_t)NN * 128;           // 2*384*128
    unsigned short* aWT  = BfT + 2 * 384 * 128;               // 2*128*128
    unsigned short* fcWT = aWT + 2 * 128 * 128;               // 64*128
    int* deg       = (int*)(fcWT + 64 * 128);                 // NN
    int* offs      = deg + NN;
    int* cursor    = offs + NN;
    int* srcSorted = cursor + NN;                             // NE

    hipMemsetAsync(deg, 0, (size_t)NN * sizeof(int), stream);
    prep_kernel<<<WBLOCKS + HBLOCKS, 256, 0, stream>>>(
        Wq, bq, Wk, bk, a_rel, Wv, bv, m_rel, p_rel, aW, fcW,
        BfT, biasf, aWT, fcWT, eidx, deg);
    scan_kernel<<<1, 1024, 0, stream>>>(deg, offs, cursor);
    scatter_kernel<<<(NE + 255) / 256, 256, 0, stream>>>(eidx, cursor, srcSorted);

    // ---- layer 0 ----
    qkv0_kernel<<<625, 256, 0, stream>>>(x, BfT, biasf, qb, kvb);
    aggregate_kernel<<<NN / 4, 256, 0, stream>>>(qb, kvb, deg, offs, srcSorted, aggb);

    // ---- fused: out-GEMM(0) -> h0 -> QKV(1) ----
    fused_kernel<0, 0><<<625, 256, 0, stream>>>(
        aggb, aWT, ab, skip, x, nullptr, hb,
        BfT + 49152, biasf + 384, qb, kvb, nullptr);
    aggregate_kernel<<<NN / 4, 256, 0, stream>>>(qb, kvb, deg, offs, srcSorted, aggb);

    // ---- fused: out-GEMM(1) -> h1 (LDS) -> fc ----
    fused_kernel<1, 2><<<625, 256, 0, stream>>>(
        aggb, aWT + 16384, ab + 128, skip + 1, nullptr, hb, nullptr,
        fcWT, fcb, nullptr, nullptr, out);
}

// Round 9
// 325.856 us; speedup vs baseline: 1.1990x; 1.1990x over previous
//
#include <hip/hip_runtime.h>
#include <hip/hip_bf16.h>
#include <math.h>

#define NN 40000
#define NE 640000
#define NB_SCAN 157   // ceil(NN/256)

typedef __attribute__((ext_vector_type(8))) short short8;
typedef __attribute__((ext_vector_type(8))) unsigned short u16x8;
typedef __attribute__((ext_vector_type(4))) float f32x4;
typedef _Float16 h16x2 __attribute__((ext_vector_type(2)));

#define WBLOCKS 547   // weight-prep blocks (547*256 = exactly the prep items)
#define HBLOCKS 2500  // hist blocks

#if __has_builtin(__builtin_amdgcn_fdot2)
#define HAS_FDOT2 1
#else
#define HAS_FDOT2 0
#endif

__device__ __forceinline__ float gelu_tanh(float x) {
    float x3 = x * x * x;
    float u = 0.7978845608028654f * (x + 0.044715f * x3);
    return 0.5f * x * (1.0f + tanhf(u));
}

__device__ __forceinline__ unsigned short f2bf(float v) {
    __hip_bfloat16 h = __float2bfloat16(v);
    return *reinterpret_cast<unsigned short*>(&h);
}

__device__ __forceinline__ unsigned short f2h(float v) {
    union { _Float16 h; unsigned short u; } c;
    c.h = (_Float16)v;
    return c.u;
}

__device__ __forceinline__ float bf2f(unsigned short u) {
    union { unsigned int i; float f; } c;
    c.i = ((unsigned int)u) << 16;
    return c.f;
}

// unpack 8 bf16 -> 8 f32 (2 ops per pair)
__device__ __forceinline__ void unpack8(u16x8 u, float* f) {
    union { u16x8 v; unsigned int d[4]; } c; c.v = u;
    #pragma unroll
    for (int i = 0; i < 4; ++i) {
        union { unsigned int i_; float f_; } lo, hi;
        lo.i_ = c.d[i] << 16;
        hi.i_ = c.d[i] & 0xffff0000u;
        f[2 * i] = lo.f_;
        f[2 * i + 1] = hi.f_;
    }
}

union kv8 { u16x8 u; h16x2 p[4]; _Float16 h[8]; };

// ---------------- prep: weights (blocks 0..546) + degree histogram (rest) -------
__global__ __launch_bounds__(256) void prep_kernel(
    const float* __restrict__ Wq, const float* __restrict__ bq,
    const float* __restrict__ Wk, const float* __restrict__ bk,
    const float* __restrict__ a_rel,
    const float* __restrict__ Wv, const float* __restrict__ bv,
    const float* __restrict__ m_rel,
    const float* __restrict__ p_rel,
    const float* __restrict__ aW, const float* __restrict__ fcW,
    unsigned short* __restrict__ BfT, float* __restrict__ biasf,
    unsigned short* __restrict__ aWT, unsigned short* __restrict__ fcWT,
    const int* __restrict__ eidx, int* __restrict__ deg)
{
    if (blockIdx.x >= WBLOCKS) {
        int e = (blockIdx.x - WBLOCKS) * 256 + threadIdx.x;
        if (e < NE) atomicAdd(&deg[eidx[NE + e]], 1);
        return;
    }
    int idx = blockIdx.x * 256 + threadIdx.x;
    if (idx < 2 * 129 * 384) {
        int l = idx / (129 * 384);
        int j = idx - l * (129 * 384);
        int r = j / 384;
        int col = j - r * 384;
        const float* Wq_l = Wq + l * 16384;
        const float* Wk_l = Wk + l * 16384;
        const float* Wv_l = Wv + l * 16384;
        const float* ar_l = a_rel + l * 2048;
        const float* mr_l = m_rel + l * 2048;
        float val;
        if (col < 128) {
            val = (r < 128) ? Wq_l[r * 128 + col] : bq[l * 128 + col];
        } else if (col < 256) {
            int cc = col - 128; int h = cc >> 4; int eo = cc & 15;
            float scale = p_rel[l * 8 + h] * 0.25f * 1.4426950408889634f;
            float s = 0.f;
            #pragma unroll
            for (int d = 0; d < 16; ++d) {
                float w = (r < 128) ? Wk_l[r * 128 + h * 16 + d] : bk[l * 128 + h * 16 + d];
                s += w * ar_l[h * 256 + d * 16 + eo];
            }
            val = s * scale;
        } else {
            int cc = col - 256; int h = cc >> 4; int eo = cc & 15;
            float s = 0.f;
            #pragma unroll
            for (int d = 0; d < 16; ++d) {
                float w = (r < 128) ? Wv_l[r * 128 + h * 16 + d] : bv[l * 128 + h * 16 + d];
                s += w * mr_l[h * 256 + d * 16 + eo];
            }
            val = s;
        }
        if (r < 128) BfT[(size_t)l * 49152 + (size_t)col * 128 + r] = f2bf(val);
        else         biasf[l * 384 + col] = val;
    } else if (idx < 2 * 129 * 384 + 2 * 16384) {
        int i = idx - 2 * 129 * 384;
        int l = i >> 14; int j = i & 16383;
        int r = j >> 7, c = j & 127;
        aWT[(size_t)l * 16384 + (size_t)c * 128 + r] = f2bf(aW[(size_t)l * 16384 + r * 128 + c]);
    } else {
        int i = idx - (2 * 129 * 384 + 2 * 16384);
        int c = i >> 7, r = i & 127;
        fcWT[(size_t)c * 128 + r] = f2bf(fcW[(size_t)r * 64 + c]);
    }
}

// ---------------- hierarchical scan (3 kernels, R7-proven) ----------------------
__global__ __launch_bounds__(256) void scan_blocks_kernel(
    const int* __restrict__ deg, int* __restrict__ offs, int* __restrict__ bsum)
{
    __shared__ int s[256];
    int t = threadIdx.x;
    int i = blockIdx.x * 256 + t;
    int v = (i < NN) ? deg[i] : 0;
    s[t] = v;
    __syncthreads();
    #pragma unroll
    for (int off = 1; off < 256; off <<= 1) {
        int u = (t >= off) ? s[t - off] : 0;
        __syncthreads();
        s[t] += u;
        __syncthreads();
    }
    if (i < NN) offs[i] = s[t] - v;
    if (t == 255) bsum[blockIdx.x] = s[255];
}

__global__ __launch_bounds__(256) void scan_top_kernel(
    const int* __restrict__ bsum, int* __restrict__ boffs)
{
    __shared__ int s[256];
    int t = threadIdx.x;
    int v = (t < NB_SCAN) ? bsum[t] : 0;
    s[t] = v;
    __syncthreads();
    #pragma unroll
    for (int off = 1; off < 256; off <<= 1) {
        int u = (t >= off) ? s[t - off] : 0;
        __syncthreads();
        s[t] += u;
        __syncthreads();
    }
    boffs[t] = s[t] - v;
}

__global__ __launch_bounds__(256) void scan_add_kernel(
    int* __restrict__ offs, const int* __restrict__ boffs, int* __restrict__ cursor)
{
    int i = blockIdx.x * 256 + threadIdx.x;
    if (i < NN) {
        int o = offs[i] + boffs[blockIdx.x];
        offs[i] = o;
        cursor[i] = o;
    }
}

__global__ __launch_bounds__(256) void scatter_kernel(
    const int* __restrict__ eidx, int* __restrict__ cursor, int* __restrict__ srcSorted)
{
    int e = blockIdx.x * 256 + threadIdx.x;
    if (e < NE) {
        int s = eidx[e];
        int d = eidx[NE + e];
        int pos = atomicAdd(&cursor[d], 1);
        srcSorted[pos] = s;
    }
}

// ---- GEMM helpers: swapped-operand MFMA (lane owns one C row, 4-col frags) ----
// qb rows: f16 [NN][128].  kvb rows: [k f16 (128) | v bf16 (128)], 512 B.

__global__ __launch_bounds__(256) void qkv0_kernel(
    const float* __restrict__ Af, const unsigned short* __restrict__ BT,
    const float* __restrict__ bias,
    unsigned short* __restrict__ qb, unsigned short* __restrict__ kvb)
{
    __shared__ unsigned short As[64][136];
    __shared__ unsigned short Bs[64][136];
    int t = threadIdx.x;
    int row0 = blockIdx.x * 64;
    int w = t >> 6;
    int lr = t & 15;
    int quad = (t & 63) >> 4;

    #pragma unroll
    for (int i = 0; i < 4; ++i) {
        int idx = t + i * 256;
        int r = idx >> 4;
        int c8 = (idx & 15) * 8;
        float4 a0 = *(const float4*)(Af + (size_t)(row0 + r) * 128 + c8);
        float4 a1 = *(const float4*)(Af + (size_t)(row0 + r) * 128 + c8 + 4);
        ushort4 u0, u1;
        u0.x = f2bf(a0.x); u0.y = f2bf(a0.y); u0.z = f2bf(a0.z); u0.w = f2bf(a0.w);
        u1.x = f2bf(a1.x); u1.y = f2bf(a1.y); u1.z = f2bf(a1.z); u1.w = f2bf(a1.w);
        *(ushort4*)(&As[r][c8]) = u0;
        *(ushort4*)(&As[r][c8 + 4]) = u1;
    }

    int row = row0 + w * 16 + lr;
    #pragma unroll
    for (int ct = 0; ct < 6; ++ct) {
        __syncthreads();
        #pragma unroll
        for (int i = 0; i < 4; ++i) {
            int idx = t + i * 256;
            int r = idx >> 4;
            int c8 = (idx & 15) * 8;
            *(u16x8*)(&Bs[r][c8]) = *(const u16x8*)(BT + (size_t)(ct * 64 + r) * 128 + c8);
        }
        __syncthreads();
        f32x4 acc[4] = {{0.f,0.f,0.f,0.f},{0.f,0.f,0.f,0.f},
                        {0.f,0.f,0.f,0.f},{0.f,0.f,0.f,0.f}};
        #pragma unroll
        for (int kc = 0; kc < 4; ++kc) {
            short8 af = *(const short8*)(&As[w * 16 + lr][kc * 32 + quad * 8]);
            #pragma unroll
            for (int n4 = 0; n4 < 4; ++n4) {
                short8 bfr = *(const short8*)(&Bs[n4 * 16 + lr][kc * 32 + quad * 8]);
                acc[n4] = __builtin_amdgcn_mfma_f32_16x16x32_bf16(bfr, af, acc[n4], 0, 0, 0);
            }
        }
        unsigned short* dst = (ct < 2) ? (qb + (size_t)row * 128 + (ct & 1) * 64)
                                       : (kvb + (size_t)row * 256 + (ct - 2) * 64);
        #pragma unroll
        for (int n4 = 0; n4 < 4; ++n4) {
            int colb = n4 * 16 + quad * 4;
            float4 bv = *(const float4*)(bias + ct * 64 + colb);
            ushort4 o;
            if (ct >= 4) {
                o.x = f2bf(acc[n4][0] + bv.x);
                o.y = f2bf(acc[n4][1] + bv.y);
                o.z = f2bf(acc[n4][2] + bv.z);
                o.w = f2bf(acc[n4][3] + bv.w);
            } else {
                o.x = f2h(acc[n4][0] + bv.x);
                o.y = f2h(acc[n4][1] + bv.y);
                o.z = f2h(acc[n4][2] + bv.z);
                o.w = f2h(acc[n4][3] + bv.w);
            }
            *(ushort4*)(dst + colb) = o;
        }
    }
}

// Fused: out-GEMM (gelu(agg)@aWT + skip -> h) then second GEMM from h (in LDS).
// HPFMT: 0 = Hprev f32, 1 = Hprev bf16.  P2: 0 = QKV out (store hb too), 2 = fc f32 out.
template <int HPFMT, int P2>
__global__ __launch_bounds__(256) void fused_kernel(
    const unsigned short* __restrict__ aggb,
    const unsigned short* __restrict__ aWT, const float* __restrict__ ab,
    const float* __restrict__ skip_p,
    const float* __restrict__ HprevF, const unsigned short* __restrict__ HprevB,
    unsigned short* __restrict__ hb_out,
    const unsigned short* __restrict__ W2T, const float* __restrict__ bias2,
    unsigned short* __restrict__ qb, unsigned short* __restrict__ kvb,
    float* __restrict__ outF)
{
    __shared__ unsigned short As[64][136];
    __shared__ unsigned short Bs[64][136];
    int t = threadIdx.x;
    int row0 = blockIdx.x * 64;
    int w = t >> 6;
    int lr = t & 15;
    int quad = (t & 63) >> 4;

    #pragma unroll
    for (int i = 0; i < 4; ++i) {
        int idx = t + i * 256;
        int r = idx >> 4;
        int c8 = (idx & 15) * 8;
        u16x8 u = *(const u16x8*)(aggb + (size_t)(row0 + r) * 128 + c8);
        #pragma unroll
        for (int j = 0; j < 8; ++j) u[j] = f2bf(gelu_tanh(bf2f(u[j])));
        *(u16x8*)(&As[r][c8]) = u;
    }

    float sv = skip_p[0];
    float beta = 1.f / (1.f + expf(-sv));
    float omb = 1.f - beta;
    int row = row0 + w * 16 + lr;

    f32x4 hacc[2][4];
    #pragma unroll
    for (int ct = 0; ct < 2; ++ct) {
        __syncthreads();
        #pragma unroll
        for (int i = 0; i < 4; ++i) {
            int idx = t + i * 256;
            int r = idx >> 4;
            int c8 = (idx & 15) * 8;
            *(u16x8*)(&Bs[r][c8]) = *(const u16x8*)(aWT + (size_t)(ct * 64 + r) * 128 + c8);
        }
        __syncthreads();
        #pragma unroll
        for (int n4 = 0; n4 < 4; ++n4) hacc[ct][n4] = (f32x4){0.f,0.f,0.f,0.f};
        #pragma unroll
        for (int kc = 0; kc < 4; ++kc) {
            short8 af = *(const short8*)(&As[w * 16 + lr][kc * 32 + quad * 8]);
            #pragma unroll
            for (int n4 = 0; n4 < 4; ++n4) {
                short8 bfr = *(const short8*)(&Bs[n4 * 16 + lr][kc * 32 + quad * 8]);
                hacc[ct][n4] = __builtin_amdgcn_mfma_f32_16x16x32_bf16(bfr, af, hacc[ct][n4], 0, 0, 0);
            }
        }
    }
    __syncthreads();

    #pragma unroll
    for (int ct = 0; ct < 2; ++ct) {
        #pragma unroll
        for (int n4 = 0; n4 < 4; ++n4) {
            int colb = ct * 64 + n4 * 16 + quad * 4;
            float4 bv = *(const float4*)(ab + colb);
            float hp[4];
            if (HPFMT == 0) {
                float4 h4 = *(const float4*)(HprevF + (size_t)row * 128 + colb);
                hp[0] = h4.x; hp[1] = h4.y; hp[2] = h4.z; hp[3] = h4.w;
            } else {
                ushort4 h4 = *(const ushort4*)(HprevB + (size_t)row * 128 + colb);
                hp[0] = bf2f(h4.x); hp[1] = bf2f(h4.y); hp[2] = bf2f(h4.z); hp[3] = bf2f(h4.w);
            }
            ushort4 o;
            o.x = f2bf(fmaxf(beta * (hacc[ct][n4][0] + bv.x) + omb * hp[0], 0.f));
            o.y = f2bf(fmaxf(beta * (hacc[ct][n4][1] + bv.y) + omb * hp[1], 0.f));
            o.z = f2bf(fmaxf(beta * (hacc[ct][n4][2] + bv.z) + omb * hp[2], 0.f));
            o.w = f2bf(fmaxf(beta * (hacc[ct][n4][3] + bv.w) + omb * hp[3], 0.f));
            *(ushort4*)(&As[w * 16 + lr][colb]) = o;
            if (P2 == 0) *(ushort4*)(hb_out + (size_t)row * 128 + colb) = o;
        }
    }
    __syncthreads();

    if (P2 == 0) {
        #pragma unroll
        for (int ct = 0; ct < 6; ++ct) {
            if (ct) __syncthreads();
            #pragma unroll
            for (int i = 0; i < 4; ++i) {
                int idx = t + i * 256;
                int r = idx >> 4;
                int c8 = (idx & 15) * 8;
                *(u16x8*)(&Bs[r][c8]) = *(const u16x8*)(W2T + (size_t)(ct * 64 + r) * 128 + c8);
            }
            __syncthreads();
            f32x4 acc[4] = {{0.f,0.f,0.f,0.f},{0.f,0.f,0.f,0.f},
                            {0.f,0.f,0.f,0.f},{0.f,0.f,0.f,0.f}};
            #pragma unroll
            for (int kc = 0; kc < 4; ++kc) {
                short8 af = *(const short8*)(&As[w * 16 + lr][kc * 32 + quad * 8]);
                #pragma unroll
                for (int n4 = 0; n4 < 4; ++n4) {
                    short8 bfr = *(const short8*)(&Bs[n4 * 16 + lr][kc * 32 + quad * 8]);
                    acc[n4] = __builtin_amdgcn_mfma_f32_16x16x32_bf16(bfr, af, acc[n4], 0, 0, 0);
                }
            }
            unsigned short* dst = (ct < 2) ? (qb + (size_t)row * 128 + (ct & 1) * 64)
                                           : (kvb + (size_t)row * 256 + (ct - 2) * 64);
            #pragma unroll
            for (int n4 = 0; n4 < 4; ++n4) {
                int colb = n4 * 16 + quad * 4;
                float4 bv = *(const float4*)(bias2 + ct * 64 + colb);
                ushort4 o;
                if (ct >= 4) {
                    o.x = f2bf(acc[n4][0] + bv.x);
                    o.y = f2bf(acc[n4][1] + bv.y);
                    o.z = f2bf(acc[n4][2] + bv.z);
                    o.w = f2bf(acc[n4][3] + bv.w);
                } else {
                    o.x = f2h(acc[n4][0] + bv.x);
                    o.y = f2h(acc[n4][1] + bv.y);
                    o.z = f2h(acc[n4][2] + bv.z);
                    o.w = f2h(acc[n4][3] + bv.w);
                }
                *(ushort4*)(dst + colb) = o;
            }
        }
    } else {
        #pragma unroll
        for (int i = 0; i < 4; ++i) {
            int idx = t + i * 256;
            int r = idx >> 4;
            int c8 = (idx & 15) * 8;
            *(u16x8*)(&Bs[r][c8]) = *(const u16x8*)(W2T + (size_t)r * 128 + c8);
        }
        __syncthreads();
        f32x4 acc[4] = {{0.f,0.f,0.f,0.f},{0.f,0.f,0.f,0.f},
                        {0.f,0.f,0.f,0.f},{0.f,0.f,0.f,0.f}};
        #pragma unroll
        for (int kc = 0; kc < 4; ++kc) {
            short8 af = *(const short8*)(&As[w * 16 + lr][kc * 32 + quad * 8]);
            #pragma unroll
            for (int n4 = 0; n4 < 4; ++n4) {
                short8 bfr = *(const short8*)(&Bs[n4 * 16 + lr][kc * 32 + quad * 8]);
                acc[n4] = __builtin_amdgcn_mfma_f32_16x16x32_bf16(bfr, af, acc[n4], 0, 0, 0);
            }
        }
        #pragma unroll
        for (int n4 = 0; n4 < 4; ++n4) {
            int colb = n4 * 16 + quad * 4;
            float4 bv = *(const float4*)(bias2 + colb);
            float4 o;
            o.x = acc[n4][0] + bv.x;
            o.y = acc[n4][1] + bv.y;
            o.z = acc[n4][2] + bv.z;
            o.w = acc[n4][3] + bv.w;
            *(float4*)(outF + (size_t)row * 64 + colb) = o;
        }
    }
}

// ---------------- Fused per-destination softmax + aggregation --------------------
// One wave per dst. lane = es*8 + h. kvb row = [k f16 (128)|v bf16 (128)], 512 B.
// Depth-2 register prefetch. Dot via v_dot2_f32_f16 when available.
__global__ __launch_bounds__(256) void aggregate_kernel(
    const unsigned short* __restrict__ qb, const unsigned short* __restrict__ kvb,
    const int* __restrict__ deg, const int* __restrict__ offs,
    const int* __restrict__ srcSorted, unsigned short* __restrict__ aggb)
{
    int n = (blockIdx.x * 256 + threadIdx.x) >> 6;
    int lane = threadIdx.x & 63;
    int es = lane >> 3;
    int h = lane & 7;

#if HAS_FDOT2
    h16x2 q2[8];
    {
        const h16x2* qp = (const h16x2*)(qb + (size_t)n * 128 + h * 16);
        #pragma unroll
        for (int j = 0; j < 8; ++j) q2[j] = qp[j];
    }
#else
    float q[16];
    {
        kv8 a, b;
        a.u = *(const u16x8*)(qb + (size_t)n * 128 + h * 16);
        b.u = *(const u16x8*)(qb + (size_t)n * 128 + h * 16 + 8);
        #pragma unroll
        for (int j = 0; j < 8; ++j) { q[j] = (float)a.h[j]; q[8 + j] = (float)b.h[j]; }
    }
#endif
    float acc[16];
    #pragma unroll
    for (int j = 0; j < 16; ++j) acc[j] = 0.f;
    float den = 0.f;

    int start = offs[n];
    int d = deg[n];
    if (d > 0) {
        int ng = (d + 7) >> 3;
        int lastIdx = start + d - 1;

        kv8 ka0, ka1; u16x8 vA0, vA1;
        kv8 kB0, kB1; u16x8 vB0, vB1;
        {
            int i0 = start + es; if (i0 > lastIdx) i0 = lastIdx;
            const unsigned short* p = kvb + (size_t)srcSorted[i0] * 256 + h * 16;
            ka0.u = *(const u16x8*)p;        ka1.u = *(const u16x8*)(p + 8);
            vA0 = *(const u16x8*)(p + 128);  vA1 = *(const u16x8*)(p + 136);
        }
        kB0 = ka0; kB1 = ka1; vB0 = vA0; vB1 = vA1;
        if (ng > 1) {
            int i1 = start + 8 + es; if (i1 > lastIdx) i1 = lastIdx;
            const unsigned short* p = kvb + (size_t)srcSorted[i1] * 256 + h * 16;
            kB0.u = *(const u16x8*)p;        kB1.u = *(const u16x8*)(p + 8);
            vB0 = *(const u16x8*)(p + 128);  vB1 = *(const u16x8*)(p + 136);
        }

        for (int g = 0; g < ng; ++g) {
            kv8 kC0 = ka0, kC1 = ka1; u16x8 vC0 = vA0, vC1 = vA1;
            if (g + 2 < ng) {
                int ni = start + (g + 2) * 8 + es; if (ni > lastIdx) ni = lastIdx;
                const unsigned short* p = kvb + (size_t)srcSorted[ni] * 256 + h * 16;
                kC0.u = *(const u16x8*)p;        kC1.u = *(const u16x8*)(p + 8);
                vC0 = *(const u16x8*)(p + 128);  vC1 = *(const u16x8*)(p + 136);
            }
            float pdot = 0.f;
#if HAS_FDOT2
            #pragma unroll
            for (int j = 0; j < 4; ++j) pdot = __builtin_amdgcn_fdot2(ka0.p[j], q2[j], pdot, false);
            #pragma unroll
            for (int j = 0; j < 4; ++j) pdot = __builtin_amdgcn_fdot2(ka1.p[j], q2[4 + j], pdot, false);
#else
            #pragma unroll
            for (int j = 0; j < 8; ++j) pdot = fmaf((float)ka0.h[j], q[j], pdot);
            #pragma unroll
            for (int j = 0; j < 8; ++j) pdot = fmaf((float)ka1.h[j], q[8 + j], pdot);
#endif
            float ev = (g * 8 + es < d) ? exp2f(pdot) : 0.f;
            den += ev;
            float vf[16];
            unpack8(vA0, vf); unpack8(vA1, vf + 8);
            #pragma unroll
            for (int j = 0; j < 16; ++j) acc[j] = fmaf(vf[j], ev, acc[j]);
            ka0 = kB0; ka1 = kB1; vA0 = vB0; vA1 = vB1;
            kB0 = kC0; kB1 = kC1; vB0 = vC0; vB1 = vC1;
        }
    }
    #pragma unroll
    for (int m = 8; m < 64; m <<= 1) {
        den += __shfl_xor(den, m, 64);
        #pragma unroll
        for (int j = 0; j < 16; ++j) acc[j] += __shfl_xor(acc[j], m, 64);
    }
    if (es == 0) {
        float w = 1.f / (den + 1e-16f);
        u16x8 o0, o1;
        #pragma unroll
        for (int j = 0; j < 8; ++j) {
            o0[j] = f2bf(acc[j] * w);
            o1[j] = f2bf(acc[j + 8] * w);
        }
        *(u16x8*)(aggb + (size_t)n * 128 + h * 16) = o0;
        *(u16x8*)(aggb + (size_t)n * 128 + h * 16 + 8) = o1;
    }
}

extern "C" void kernel_launch(void* const* d_in, const int* in_sizes, int n_in,
                              void* d_out, int out_size, void* d_ws, size_t ws_size,
                              hipStream_t stream) {
    const float* x     = (const float*)d_in[0];
    const int*   eidx  = (const int*)d_in[1];
    const float* Wk    = (const float*)d_in[2];
    const float* bk    = (const float*)d_in[3];
    const float* Wq    = (const float*)d_in[4];
    const float* bq    = (const float*)d_in[5];
    const float* Wv    = (const float*)d_in[6];
    const float* bv    = (const float*)d_in[7];
    const float* a_rel = (const float*)d_in[8];
    const float* m_rel = (const float*)d_in[9];
    const float* p_rel = (const float*)d_in[10];
    const float* skip  = (const float*)d_in[11];
    const float* aW    = (const float*)d_in[12];
    const float* ab    = (const float*)d_in[13];
    const float* fcW   = (const float*)d_in[14];
    const float* fcb   = (const float*)d_in[15];
    float* out = (float*)d_out;

    float* biasf = (float*)d_ws;                              // 2*384
    unsigned short* hb   = (unsigned short*)(biasf + 768);    // NN*128
    unsigned short* qb   = hb + (size_t)NN * 128;             // NN*128 (f16)
    unsigned short* kvb  = qb + (size_t)NN * 128;             // NN*256 ([k f16|v bf16])
    unsigned short* aggb = kvb + (size_t)NN * 256;            // NN*128
    unsigned short* BfT  = aggb + (size_t)NN * 128;           // 2*384*128
    unsigned short* aWT  = BfT + 2 * 384 * 128;               // 2*128*128
    unsigned short* fcWT = aWT + 2 * 128 * 128;               // 64*128
    int* deg       = (int*)(fcWT + 64 * 128);                 // NN
    int* offs      = deg + NN;
    int* cursor    = offs + NN;
    int* bsum      = cursor + NN;                             // 256
    int* boffs     = bsum + 256;                              // 256
    int* srcSorted = boffs + 256;                             // NE

    hipMemsetAsync(deg, 0, (size_t)NN * sizeof(int), stream);
    prep_kernel<<<WBLOCKS + HBLOCKS, 256, 0, stream>>>(
        Wq, bq, Wk, bk, a_rel, Wv, bv, m_rel, p_rel, aW, fcW,
        BfT, biasf, aWT, fcWT, eidx, deg);
    scan_blocks_kernel<<<NB_SCAN, 256, 0, stream>>>(deg, offs, bsum);
    scan_top_kernel<<<1, 256, 0, stream>>>(bsum, boffs);
    scan_add_kernel<<<NB_SCAN, 256, 0, stream>>>(offs, boffs, cursor);
    scatter_kernel<<<(NE + 255) / 256, 256, 0, stream>>>(eidx, cursor, srcSorted);

    // ---- layer 0 ----
    qkv0_kernel<<<625, 256, 0, stream>>>(x, BfT, biasf, qb, kvb);
    aggregate_kernel<<<NN / 4, 256, 0, stream>>>(qb, kvb, deg, offs, srcSorted, aggb);

    // ---- fused: out-GEMM(0) -> h0 -> QKV(1) ----
    fused_kernel<0, 0><<<625, 256, 0, stream>>>(
        aggb, aWT, ab, skip, x, nullptr, hb,
        BfT + 49152, biasf + 384, qb, kvb, nullptr);
    aggregate_kernel<<<NN / 4, 256, 0, stream>>>(qb, kvb, deg, offs, srcSorted, aggb);

    // ---- fused: out-GEMM(1) -> h1 (LDS) -> fc ----
    fused_kernel<1, 2><<<625, 256, 0, stream>>>(
        aggb, aWT + 16384, ab + 128, skip + 1, nullptr, hb, nullptr,
        fcWT, fcb, nullptr, nullptr, out);
}

// Round 10
// 305.934 us; speedup vs baseline: 1.2770x; 1.0651x over previous
//
#include <hip/hip_runtime.h>
#include <hip/hip_bf16.h>
#include <math.h>

#define NN 40000
#define NE 640000
#define NB_SCAN 157   // ceil(NN/256)

typedef __attribute__((ext_vector_type(8))) short short8;
typedef __attribute__((ext_vector_type(8))) unsigned short u16x8;
typedef __attribute__((ext_vector_type(4))) float f32x4;
typedef _Float16 h16x2 __attribute__((ext_vector_type(2)));

#define WBLOCKS 547   // weight-prep blocks
#define HBLOCKS 2500  // hist blocks
#define GBLOCKS 625   // GEMM row blocks (NN/64)

#if __has_builtin(__builtin_amdgcn_fdot2)
#define HAS_FDOT2 1
#else
#define HAS_FDOT2 0
#endif

__device__ __forceinline__ float gelu_tanh(float x) {
    float x3 = x * x * x;
    float u = 0.7978845608028654f * (x + 0.044715f * x3);
    return 0.5f * x * (1.0f + tanhf(u));
}

__device__ __forceinline__ unsigned short f2bf(float v) {
    __hip_bfloat16 h = __float2bfloat16(v);
    return *reinterpret_cast<unsigned short*>(&h);
}

__device__ __forceinline__ unsigned short f2h(float v) {
    union { _Float16 h; unsigned short u; } c;
    c.h = (_Float16)v;
    return c.u;
}

__device__ __forceinline__ float bf2f(unsigned short u) {
    union { unsigned int i; float f; } c;
    c.i = ((unsigned int)u) << 16;
    return c.f;
}

__device__ __forceinline__ void unpack8(u16x8 u, float* f) {
    union { u16x8 v; unsigned int d[4]; } c; c.v = u;
    #pragma unroll
    for (int i = 0; i < 4; ++i) {
        union { unsigned int i_; float f_; } lo, hi;
        lo.i_ = c.d[i] << 16;
        hi.i_ = c.d[i] & 0xffff0000u;
        f[2 * i] = lo.f_;
        f[2 * i + 1] = hi.f_;
    }
}

union kv8 { u16x8 u; h16x2 p[4]; _Float16 h[8]; };
union frag8 { short8 s; unsigned short u[8]; u16x8 v; };

// ---------------- prep: weights (blocks 0..546) + degree histogram (rest) -------
__global__ __launch_bounds__(256) void prep_kernel(
    const float* __restrict__ Wq, const float* __restrict__ bq,
    const float* __restrict__ Wk, const float* __restrict__ bk,
    const float* __restrict__ a_rel,
    const float* __restrict__ Wv, const float* __restrict__ bv,
    const float* __restrict__ m_rel,
    const float* __restrict__ p_rel,
    const float* __restrict__ aW, const float* __restrict__ fcW,
    unsigned short* __restrict__ BfT, float* __restrict__ biasf,
    unsigned short* __restrict__ aWT, unsigned short* __restrict__ fcWT,
    const int* __restrict__ eidx, int* __restrict__ deg)
{
    if (blockIdx.x >= WBLOCKS) {
        int e = (blockIdx.x - WBLOCKS) * 256 + threadIdx.x;
        if (e < NE) atomicAdd(&deg[eidx[NE + e]], 1);
        return;
    }
    int idx = blockIdx.x * 256 + threadIdx.x;
    if (idx < 2 * 129 * 384) {
        int l = idx / (129 * 384);
        int j = idx - l * (129 * 384);
        int r = j / 384;
        int col = j - r * 384;
        const float* Wq_l = Wq + l * 16384;
        const float* Wk_l = Wk + l * 16384;
        const float* Wv_l = Wv + l * 16384;
        const float* ar_l = a_rel + l * 2048;
        const float* mr_l = m_rel + l * 2048;
        float val;
        if (col < 128) {
            val = (r < 128) ? Wq_l[r * 128 + col] : bq[l * 128 + col];
        } else if (col < 256) {
            int cc = col - 128; int h = cc >> 4; int eo = cc & 15;
            float scale = p_rel[l * 8 + h] * 0.25f * 1.4426950408889634f;
            float s = 0.f;
            #pragma unroll
            for (int d = 0; d < 16; ++d) {
                float w = (r < 128) ? Wk_l[r * 128 + h * 16 + d] : bk[l * 128 + h * 16 + d];
                s += w * ar_l[h * 256 + d * 16 + eo];
            }
            val = s * scale;
        } else {
            int cc = col - 256; int h = cc >> 4; int eo = cc & 15;
            float s = 0.f;
            #pragma unroll
            for (int d = 0; d < 16; ++d) {
                float w = (r < 128) ? Wv_l[r * 128 + h * 16 + d] : bv[l * 128 + h * 16 + d];
                s += w * mr_l[h * 256 + d * 16 + eo];
            }
            val = s;
        }
        if (r < 128) BfT[(size_t)l * 49152 + (size_t)col * 128 + r] = f2bf(val);
        else         biasf[l * 384 + col] = val;
    } else if (idx < 2 * 129 * 384 + 2 * 16384) {
        int i = idx - 2 * 129 * 384;
        int l = i >> 14; int j = i & 16383;
        int r = j >> 7, c = j & 127;
        aWT[(size_t)l * 16384 + (size_t)c * 128 + r] = f2bf(aW[(size_t)l * 16384 + r * 128 + c]);
    } else {
        int i = idx - (2 * 129 * 384 + 2 * 16384);
        int c = i >> 7, r = i & 127;
        fcWT[(size_t)c * 128 + r] = f2bf(fcW[(size_t)r * 64 + c]);
    }
}

// ---------------- hierarchical scan (3 kernels) ----------------------------------
__global__ __launch_bounds__(256) void scan_blocks_kernel(
    const int* __restrict__ deg, int* __restrict__ offs, int* __restrict__ bsum)
{
    __shared__ int s[256];
    int t = threadIdx.x;
    int i = blockIdx.x * 256 + t;
    int v = (i < NN) ? deg[i] : 0;
    s[t] = v;
    __syncthreads();
    #pragma unroll
    for (int off = 1; off < 256; off <<= 1) {
        int u = (t >= off) ? s[t - off] : 0;
        __syncthreads();
        s[t] += u;
        __syncthreads();
    }
    if (i < NN) offs[i] = s[t] - v;
    if (t == 255) bsum[blockIdx.x] = s[255];
}

__global__ __launch_bounds__(256) void scan_top_kernel(
    const int* __restrict__ bsum, int* __restrict__ boffs)
{
    __shared__ int s[256];
    int t = threadIdx.x;
    int v = (t < NB_SCAN) ? bsum[t] : 0;
    s[t] = v;
    __syncthreads();
    #pragma unroll
    for (int off = 1; off < 256; off <<= 1) {
        int u = (t >= off) ? s[t - off] : 0;
        __syncthreads();
        s[t] += u;
        __syncthreads();
    }
    boffs[t] = s[t] - v;
}

__global__ __launch_bounds__(256) void scan_add_kernel(
    int* __restrict__ offs, const int* __restrict__ boffs, int* __restrict__ cursor)
{
    int i = blockIdx.x * 256 + threadIdx.x;
    if (i < NN) {
        int o = offs[i] + boffs[blockIdx.x];
        offs[i] = o;
        cursor[i] = o;
    }
}

// ---- qkv0 (blocks 0..624) merged with scatter (blocks 625..3124) ---------------
// Direct-register A fragments (no A LDS stage); Bs per ct tile in LDS.
// qb rows: f16 [NN][128].  kvb rows: [k f16 (128) | v bf16 (128)], 512 B.
__global__ __launch_bounds__(256) void qkv0_scatter_kernel(
    const float* __restrict__ Af, const unsigned short* __restrict__ BT,
    const float* __restrict__ bias,
    unsigned short* __restrict__ qb, unsigned short* __restrict__ kvb,
    const int* __restrict__ eidx, int* __restrict__ cursor,
    int* __restrict__ srcSorted)
{
    if (blockIdx.x >= GBLOCKS) {
        int e = (blockIdx.x - GBLOCKS) * 256 + threadIdx.x;
        int s = eidx[e];
        int d = eidx[NE + e];
        int pos = atomicAdd(&cursor[d], 1);
        srcSorted[pos] = s;
        return;
    }
    __shared__ unsigned short Bs[64][136];
    int t = threadIdx.x;
    int row0 = blockIdx.x * 64;
    int w = t >> 6;
    int lr = t & 15;
    int quad = (t & 63) >> 4;
    int row = row0 + w * 16 + lr;

    // per-lane A fragments, reused for all 6 column tiles
    frag8 af[4];
    {
        const float* ap = Af + (size_t)row * 128 + quad * 8;
        #pragma unroll
        for (int kc = 0; kc < 4; ++kc) {
            float4 a0 = *(const float4*)(ap + kc * 32);
            float4 a1 = *(const float4*)(ap + kc * 32 + 4);
            af[kc].u[0] = f2bf(a0.x); af[kc].u[1] = f2bf(a0.y);
            af[kc].u[2] = f2bf(a0.z); af[kc].u[3] = f2bf(a0.w);
            af[kc].u[4] = f2bf(a1.x); af[kc].u[5] = f2bf(a1.y);
            af[kc].u[6] = f2bf(a1.z); af[kc].u[7] = f2bf(a1.w);
        }
    }

    #pragma unroll
    for (int ct = 0; ct < 6; ++ct) {
        if (ct) __syncthreads();
        #pragma unroll
        for (int i = 0; i < 4; ++i) {
            int idx = t + i * 256;
            int r = idx >> 4;
            int c8 = (idx & 15) * 8;
            *(u16x8*)(&Bs[r][c8]) = *(const u16x8*)(BT + (size_t)(ct * 64 + r) * 128 + c8);
        }
        __syncthreads();
        f32x4 acc[4] = {{0.f,0.f,0.f,0.f},{0.f,0.f,0.f,0.f},
                        {0.f,0.f,0.f,0.f},{0.f,0.f,0.f,0.f}};
        #pragma unroll
        for (int kc = 0; kc < 4; ++kc) {
            #pragma unroll
            for (int n4 = 0; n4 < 4; ++n4) {
                short8 bfr = *(const short8*)(&Bs[n4 * 16 + lr][kc * 32 + quad * 8]);
                acc[n4] = __builtin_amdgcn_mfma_f32_16x16x32_bf16(bfr, af[kc].s, acc[n4], 0, 0, 0);
            }
        }
        unsigned short* dst = (ct < 2) ? (qb + (size_t)row * 128 + (ct & 1) * 64)
                                       : (kvb + (size_t)row * 256 + (ct - 2) * 64);
        #pragma unroll
        for (int n4 = 0; n4 < 4; ++n4) {
            int colb = n4 * 16 + quad * 4;
            float4 bv = *(const float4*)(bias + ct * 64 + colb);
            ushort4 o;
            if (ct >= 4) {
                o.x = f2bf(acc[n4][0] + bv.x);
                o.y = f2bf(acc[n4][1] + bv.y);
                o.z = f2bf(acc[n4][2] + bv.z);
                o.w = f2bf(acc[n4][3] + bv.w);
            } else {
                o.x = f2h(acc[n4][0] + bv.x);
                o.y = f2h(acc[n4][1] + bv.y);
                o.z = f2h(acc[n4][2] + bv.z);
                o.w = f2h(acc[n4][3] + bv.w);
            }
            *(ushort4*)(dst + colb) = o;
        }
    }
}

// Fused: out-GEMM (gelu(agg)@aWT + skip -> h) then second GEMM from h (in LDS).
// Phase-1 A fragments loaded direct global->reg (no LDS stage).
// HPFMT: 0 = Hprev f32, 1 = Hprev bf16.  P2: 0 = QKV out (store hb too), 2 = fc out.
template <int HPFMT, int P2>
__global__ __launch_bounds__(256) void fused_kernel(
    const unsigned short* __restrict__ aggb,
    const unsigned short* __restrict__ aWT, const float* __restrict__ ab,
    const float* __restrict__ skip_p,
    const float* __restrict__ HprevF, const unsigned short* __restrict__ HprevB,
    unsigned short* __restrict__ hb_out,
    const unsigned short* __restrict__ W2T, const float* __restrict__ bias2,
    unsigned short* __restrict__ qb, unsigned short* __restrict__ kvb,
    float* __restrict__ outF)
{
    __shared__ unsigned short As[64][136];   // holds h tile for phase 2
    __shared__ unsigned short Bs[64][136];
    int t = threadIdx.x;
    int row0 = blockIdx.x * 64;
    int w = t >> 6;
    int lr = t & 15;
    int quad = (t & 63) >> 4;
    int row = row0 + w * 16 + lr;

    // phase-1 A fragments: gelu(aggb) direct to registers
    frag8 agf[4];
    {
        const unsigned short* ap = aggb + (size_t)row * 128 + quad * 8;
        #pragma unroll
        for (int kc = 0; kc < 4; ++kc) {
            u16x8 u = *(const u16x8*)(ap + kc * 32);
            #pragma unroll
            for (int j = 0; j < 8; ++j) agf[kc].u[j] = f2bf(gelu_tanh(bf2f(u[j])));
        }
    }

    float sv = skip_p[0];
    float beta = 1.f / (1.f + expf(-sv));
    float omb = 1.f - beta;

    f32x4 hacc[2][4];
    #pragma unroll
    for (int ct = 0; ct < 2; ++ct) {
        if (ct) __syncthreads();
        #pragma unroll
        for (int i = 0; i < 4; ++i) {
            int idx = t + i * 256;
            int r = idx >> 4;
            int c8 = (idx & 15) * 8;
            *(u16x8*)(&Bs[r][c8]) = *(const u16x8*)(aWT + (size_t)(ct * 64 + r) * 128 + c8);
        }
        __syncthreads();
        #pragma unroll
        for (int n4 = 0; n4 < 4; ++n4) hacc[ct][n4] = (f32x4){0.f,0.f,0.f,0.f};
        #pragma unroll
        for (int kc = 0; kc < 4; ++kc) {
            #pragma unroll
            for (int n4 = 0; n4 < 4; ++n4) {
                short8 bfr = *(const short8*)(&Bs[n4 * 16 + lr][kc * 32 + quad * 8]);
                hacc[ct][n4] = __builtin_amdgcn_mfma_f32_16x16x32_bf16(bfr, agf[kc].s, hacc[ct][n4], 0, 0, 0);
            }
        }
    }

    // epilogue: h = relu(beta*(.)+ (1-beta)*Hprev) -> As (LDS) [+ hb global]
    #pragma unroll
    for (int ct = 0; ct < 2; ++ct) {
        #pragma unroll
        for (int n4 = 0; n4 < 4; ++n4) {
            int colb = ct * 64 + n4 * 16 + quad * 4;
            float4 bv = *(const float4*)(ab + colb);
            float hp[4];
            if (HPFMT == 0) {
                float4 h4 = *(const float4*)(HprevF + (size_t)row * 128 + colb);
                hp[0] = h4.x; hp[1] = h4.y; hp[2] = h4.z; hp[3] = h4.w;
            } else {
                ushort4 h4 = *(const ushort4*)(HprevB + (size_t)row * 128 + colb);
                hp[0] = bf2f(h4.x); hp[1] = bf2f(h4.y); hp[2] = bf2f(h4.z); hp[3] = bf2f(h4.w);
            }
            ushort4 o;
            o.x = f2bf(fmaxf(beta * (hacc[ct][n4][0] + bv.x) + omb * hp[0], 0.f));
            o.y = f2bf(fmaxf(beta * (hacc[ct][n4][1] + bv.y) + omb * hp[1], 0.f));
            o.z = f2bf(fmaxf(beta * (hacc[ct][n4][2] + bv.z) + omb * hp[2], 0.f));
            o.w = f2bf(fmaxf(beta * (hacc[ct][n4][3] + bv.w) + omb * hp[3], 0.f));
            *(ushort4*)(&As[w * 16 + lr][colb]) = o;
            if (P2 == 0) *(ushort4*)(hb_out + (size_t)row * 128 + colb) = o;
        }
    }
    __syncthreads();   // h tile ready; also guards last Bs reads of phase 1

    if (P2 == 0) {
        #pragma unroll
        for (int ct = 0; ct < 6; ++ct) {
            if (ct) __syncthreads();
            #pragma unroll
            for (int i = 0; i < 4; ++i) {
                int idx = t + i * 256;
                int r = idx >> 4;
                int c8 = (idx & 15) * 8;
                *(u16x8*)(&Bs[r][c8]) = *(const u16x8*)(W2T + (size_t)(ct * 64 + r) * 128 + c8);
            }
            __syncthreads();
            f32x4 acc[4] = {{0.f,0.f,0.f,0.f},{0.f,0.f,0.f,0.f},
                            {0.f,0.f,0.f,0.f},{0.f,0.f,0.f,0.f}};
            #pragma unroll
            for (int kc = 0; kc < 4; ++kc) {
                short8 afr = *(const short8*)(&As[w * 16 + lr][kc * 32 + quad * 8]);
                #pragma unroll
                for (int n4 = 0; n4 < 4; ++n4) {
                    short8 bfr = *(const short8*)(&Bs[n4 * 16 + lr][kc * 32 + quad * 8]);
                    acc[n4] = __builtin_amdgcn_mfma_f32_16x16x32_bf16(bfr, afr, acc[n4], 0, 0, 0);
                }
            }
            unsigned short* dst = (ct < 2) ? (qb + (size_t)row * 128 + (ct & 1) * 64)
                                           : (kvb + (size_t)row * 256 + (ct - 2) * 64);
            #pragma unroll
            for (int n4 = 0; n4 < 4; ++n4) {
                int colb = n4 * 16 + quad * 4;
                float4 bv = *(const float4*)(bias2 + ct * 64 + colb);
                ushort4 o;
                if (ct >= 4) {
                    o.x = f2bf(acc[n4][0] + bv.x);
                    o.y = f2bf(acc[n4][1] + bv.y);
                    o.z = f2bf(acc[n4][2] + bv.z);
                    o.w = f2bf(acc[n4][3] + bv.w);
                } else {
                    o.x = f2h(acc[n4][0] + bv.x);
                    o.y = f2h(acc[n4][1] + bv.y);
                    o.z = f2h(acc[n4][2] + bv.z);
                    o.w = f2h(acc[n4][3] + bv.w);
                }
                *(ushort4*)(dst + colb) = o;
            }
        }
    } else {
        #pragma unroll
        for (int i = 0; i < 4; ++i) {
            int idx = t + i * 256;
            int r = idx >> 4;
            int c8 = (idx & 15) * 8;
            *(u16x8*)(&Bs[r][c8]) = *(const u16x8*)(W2T + (size_t)r * 128 + c8);
        }
        __syncthreads();
        f32x4 acc[4] = {{0.f,0.f,0.f,0.f},{0.f,0.f,0.f,0.f},
                        {0.f,0.f,0.f,0.f},{0.f,0.f,0.f,0.f}};
        #pragma unroll
        for (int kc = 0; kc < 4; ++kc) {
            short8 afr = *(const short8*)(&As[w * 16 + lr][kc * 32 + quad * 8]);
            #pragma unroll
            for (int n4 = 0; n4 < 4; ++n4) {
                short8 bfr = *(const short8*)(&Bs[n4 * 16 + lr][kc * 32 + quad * 8]);
                acc[n4] = __builtin_amdgcn_mfma_f32_16x16x32_bf16(bfr, afr, acc[n4], 0, 0, 0);
            }
        }
        #pragma unroll
        for (int n4 = 0; n4 < 4; ++n4) {
            int colb = n4 * 16 + quad * 4;
            float4 bv = *(const float4*)(bias2 + colb);
            float4 o;
            o.x = acc[n4][0] + bv.x;
            o.y = acc[n4][1] + bv.y;
            o.z = acc[n4][2] + bv.z;
            o.w = acc[n4][3] + bv.w;
            *(float4*)(outF + (size_t)row * 64 + colb) = o;
        }
    }
}

// ---------------- Fused per-destination softmax + aggregation --------------------
__global__ __launch_bounds__(256) void aggregate_kernel(
    const unsigned short* __restrict__ qb, const unsigned short* __restrict__ kvb,
    const int* __restrict__ deg, const int* __restrict__ offs,
    const int* __restrict__ srcSorted, unsigned short* __restrict__ aggb)
{
    int n = (blockIdx.x * 256 + threadIdx.x) >> 6;
    int lane = threadIdx.x & 63;
    int es = lane >> 3;
    int h = lane & 7;

#if HAS_FDOT2
    h16x2 q2[8];
    {
        const h16x2* qp = (const h16x2*)(qb + (size_t)n * 128 + h * 16);
        #pragma unroll
        for (int j = 0; j < 8; ++j) q2[j] = qp[j];
    }
#else
    float q[16];
    {
        kv8 a, b;
        a.u = *(const u16x8*)(qb + (size_t)n * 128 + h * 16);
        b.u = *(const u16x8*)(qb + (size_t)n * 128 + h * 16 + 8);
        #pragma unroll
        for (int j = 0; j < 8; ++j) { q[j] = (float)a.h[j]; q[8 + j] = (float)b.h[j]; }
    }
#endif
    float acc[16];
    #pragma unroll
    for (int j = 0; j < 16; ++j) acc[j] = 0.f;
    float den = 0.f;

    int start = offs[n];
    int d = deg[n];
    if (d > 0) {
        int ng = (d + 7) >> 3;
        int lastIdx = start + d - 1;

        kv8 ka0, ka1; u16x8 vA0, vA1;
        kv8 kB0, kB1; u16x8 vB0, vB1;
        {
            int i0 = start + es; if (i0 > lastIdx) i0 = lastIdx;
            const unsigned short* p = kvb + (size_t)srcSorted[i0] * 256 + h * 16;
            ka0.u = *(const u16x8*)p;        ka1.u = *(const u16x8*)(p + 8);
            vA0 = *(const u16x8*)(p + 128);  vA1 = *(const u16x8*)(p + 136);
        }
        kB0 = ka0; kB1 = ka1; vB0 = vA0; vB1 = vA1;
        if (ng > 1) {
            int i1 = start + 8 + es; if (i1 > lastIdx) i1 = lastIdx;
            const unsigned short* p = kvb + (size_t)srcSorted[i1] * 256 + h * 16;
            kB0.u = *(const u16x8*)p;        kB1.u = *(const u16x8*)(p + 8);
            vB0 = *(const u16x8*)(p + 128);  vB1 = *(const u16x8*)(p + 136);
        }

        for (int g = 0; g < ng; ++g) {
            kv8 kC0 = ka0, kC1 = ka1; u16x8 vC0 = vA0, vC1 = vA1;
            if (g + 2 < ng) {
                int ni = start + (g + 2) * 8 + es; if (ni > lastIdx) ni = lastIdx;
                const unsigned short* p = kvb + (size_t)srcSorted[ni] * 256 + h * 16;
                kC0.u = *(const u16x8*)p;        kC1.u = *(const u16x8*)(p + 8);
                vC0 = *(const u16x8*)(p + 128);  vC1 = *(const u16x8*)(p + 136);
            }
            float pdot = 0.f;
#if HAS_FDOT2
            #pragma unroll
            for (int j = 0; j < 4; ++j) pdot = __builtin_amdgcn_fdot2(ka0.p[j], q2[j], pdot, false);
            #pragma unroll
            for (int j = 0; j < 4; ++j) pdot = __builtin_amdgcn_fdot2(ka1.p[j], q2[4 + j], pdot, false);
#else
            #pragma unroll
            for (int j = 0; j < 8; ++j) pdot = fmaf((float)ka0.h[j], q[j], pdot);
            #pragma unroll
            for (int j = 0; j < 8; ++j) pdot = fmaf((float)ka1.h[j], q[8 + j], pdot);
#endif
            float ev = (g * 8 + es < d) ? exp2f(pdot) : 0.f;
            den += ev;
            float vf[16];
            unpack8(vA0, vf); unpack8(vA1, vf + 8);
            #pragma unroll
            for (int j = 0; j < 16; ++j) acc[j] = fmaf(vf[j], ev, acc[j]);
            ka0 = kB0; ka1 = kB1; vA0 = vB0; vA1 = vB1;
            kB0 = kC0; kB1 = kC1; vB0 = vC0; vB1 = vC1;
        }
    }
    #pragma unroll
    for (int m = 8; m < 64; m <<= 1) {
        den += __shfl_xor(den, m, 64);
        #pragma unroll
        for (int j = 0; j < 16; ++j) acc[j] += __shfl_xor(acc[j], m, 64);
    }
    if (es == 0) {
        float w = 1.f / (den + 1e-16f);
        u16x8 o0, o1;
        #pragma unroll
        for (int j = 0; j < 8; ++j) {
            o0[j] = f2bf(acc[j] * w);
            o1[j] = f2bf(acc[j + 8] * w);
        }
        *(u16x8*)(aggb + (size_t)n * 128 + h * 16) = o0;
        *(u16x8*)(aggb + (size_t)n * 128 + h * 16 + 8) = o1;
    }
}

extern "C" void kernel_launch(void* const* d_in, const int* in_sizes, int n_in,
                              void* d_out, int out_size, void* d_ws, size_t ws_size,
                              hipStream_t stream) {
    const float* x     = (const float*)d_in[0];
    const int*   eidx  = (const int*)d_in[1];
    const float* Wk    = (const float*)d_in[2];
    const float* bk    = (const float*)d_in[3];
    const float* Wq    = (const float*)d_in[4];
    const float* bq    = (const float*)d_in[5];
    const float* Wv    = (const float*)d_in[6];
    const float* bv    = (const float*)d_in[7];
    const float* a_rel = (const float*)d_in[8];
    const float* m_rel = (const float*)d_in[9];
    const float* p_rel = (const float*)d_in[10];
    const float* skip  = (const float*)d_in[11];
    const float* aW    = (const float*)d_in[12];
    const float* ab    = (const float*)d_in[13];
    const float* fcW   = (const float*)d_in[14];
    const float* fcb   = (const float*)d_in[15];
    float* out = (float*)d_out;

    float* biasf = (float*)d_ws;                              // 2*384
    unsigned short* hb   = (unsigned short*)(biasf + 768);    // NN*128
    unsigned short* qb   = hb + (size_t)NN * 128;             // NN*128 (f16)
    unsigned short* kvb  = qb + (size_t)NN * 128;             // NN*256 ([k f16|v bf16])
    unsigned short* aggb = kvb + (size_t)NN * 256;            // NN*128
    unsigned short* BfT  = aggb + (size_t)NN * 128;           // 2*384*128
    unsigned short* aWT  = BfT + 2 * 384 * 128;               // 2*128*128
    unsigned short* fcWT = aWT + 2 * 128 * 128;               // 64*128
    int* deg       = (int*)(fcWT + 64 * 128);                 // NN
    int* offs      = deg + NN;
    int* cursor    = offs + NN;
    int* bsum      = cursor + NN;                             // 256
    int* boffs     = bsum + 256;                              // 256
    int* srcSorted = boffs + 256;                             // NE

    hipMemsetAsync(deg, 0, (size_t)NN * sizeof(int), stream);
    prep_kernel<<<WBLOCKS + HBLOCKS, 256, 0, stream>>>(
        Wq, bq, Wk, bk, a_rel, Wv, bv, m_rel, p_rel, aW, fcW,
        BfT, biasf, aWT, fcWT, eidx, deg);
    scan_blocks_kernel<<<NB_SCAN, 256, 0, stream>>>(deg, offs, bsum);
    scan_top_kernel<<<1, 256, 0, stream>>>(bsum, boffs);
    scan_add_kernel<<<NB_SCAN, 256, 0, stream>>>(offs, boffs, cursor);

    // ---- layer 0 QKV + edge scatter (independent, co-scheduled) ----
    qkv0_scatter_kernel<<<GBLOCKS + HBLOCKS, 256, 0, stream>>>(
        x, BfT, biasf, qb, kvb, eidx, cursor, srcSorted);
    aggregate_kernel<<<NN / 4, 256, 0, stream>>>(qb, kvb, deg, offs, srcSorted, aggb);

    // ---- fused: out-GEMM(0) -> h0 -> QKV(1) ----
    fused_kernel<0, 0><<<GBLOCKS, 256, 0, stream>>>(
        aggb, aWT, ab, skip, x, nullptr, hb,
        BfT + 49152, biasf + 384, qb, kvb, nullptr);
    aggregate_kernel<<<NN / 4, 256, 0, stream>>>(qb, kvb, deg, offs, srcSorted, aggb);

    // ---- fused: out-GEMM(1) -> h1 (LDS) -> fc ----
    fused_kernel<1, 2><<<GBLOCKS, 256, 0, stream>>>(
        aggb, aWT + 16384, ab + 128, skip + 1, nullptr, hb, nullptr,
        fcWT, fcb, nullptr, nullptr, out);
}

// Round 11
// 269.818 us; speedup vs baseline: 1.4480x; 1.1339x over previous
//
#include <hip/hip_runtime.h>
#include <hip/hip_bf16.h>
#include <math.h>

#define NN 40000
#define NE 640000

typedef __attribute__((ext_vector_type(8))) short short8;
typedef __attribute__((ext_vector_type(8))) unsigned short u16x8;
typedef __attribute__((ext_vector_type(4))) float f32x4;
typedef _Float16 h16x2 __attribute__((ext_vector_type(2)));

#define WBLOCKS 547   // weight-prep blocks
#define GBLOCKS 625   // GEMM row blocks (NN/64)
#define NCO 157       // coarse buckets (dst>>8)
#define P1B 160       // pass1/pass2 blocks
#define EPB 4000      // edges per pass1/2 block (NE/P1B)
#define NH (NCO*P1B)  // 25120 histogram cells
#define NHB 99        // ceil(NH/256)

#if __has_builtin(__builtin_amdgcn_fdot2)
#define HAS_FDOT2 1
#else
#define HAS_FDOT2 0
#endif

__device__ __forceinline__ float gelu_tanh(float x) {
    float x3 = x * x * x;
    float u = 0.7978845608028654f * (x + 0.044715f * x3);
    return 0.5f * x * (1.0f + tanhf(u));
}

__device__ __forceinline__ unsigned short f2bf(float v) {
    __hip_bfloat16 h = __float2bfloat16(v);
    return *reinterpret_cast<unsigned short*>(&h);
}

__device__ __forceinline__ unsigned short f2h(float v) {
    union { _Float16 h; unsigned short u; } c;
    c.h = (_Float16)v;
    return c.u;
}

__device__ __forceinline__ float bf2f(unsigned short u) {
    union { unsigned int i; float f; } c;
    c.i = ((unsigned int)u) << 16;
    return c.f;
}

__device__ __forceinline__ void unpack8(u16x8 u, float* f) {
    union { u16x8 v; unsigned int d[4]; } c; c.v = u;
    #pragma unroll
    for (int i = 0; i < 4; ++i) {
        union { unsigned int i_; float f_; } lo, hi;
        lo.i_ = c.d[i] << 16;
        hi.i_ = c.d[i] & 0xffff0000u;
        f[2 * i] = lo.f_;
        f[2 * i + 1] = hi.f_;
    }
}

union kv8 { u16x8 u; h16x2 p[4]; _Float16 h[8]; };
union frag8 { short8 s; unsigned short u[8]; u16x8 v; };

// ---------------- prep: weights (blocks 0..546) + coarse hist pass1 (rest) ------
__global__ __launch_bounds__(256) void prep_kernel(
    const float* __restrict__ Wq, const float* __restrict__ bq,
    const float* __restrict__ Wk, const float* __restrict__ bk,
    const float* __restrict__ a_rel,
    const float* __restrict__ Wv, const float* __restrict__ bv,
    const float* __restrict__ m_rel,
    const float* __restrict__ p_rel,
    const float* __restrict__ aW, const float* __restrict__ fcW,
    unsigned short* __restrict__ BfT, float* __restrict__ biasf,
    unsigned short* __restrict__ aWT, unsigned short* __restrict__ fcWT,
    const int* __restrict__ eidx, int* __restrict__ Hmat)
{
    if (blockIdx.x >= WBLOCKS) {
        // pass 1: per-block coarse histogram (LDS atomics only)
        __shared__ int chist[NCO];
        int b = blockIdx.x - WBLOCKS;
        int t = threadIdx.x;
        if (t < NCO) chist[t] = 0;
        __syncthreads();
        int base = b * EPB;
        for (int e = base + t; e < base + EPB; e += 256)
            atomicAdd(&chist[eidx[NE + e] >> 8], 1);
        __syncthreads();
        if (t < NCO) Hmat[t * P1B + b] = chist[t];
        return;
    }
    int idx = blockIdx.x * 256 + threadIdx.x;
    if (idx < 2 * 129 * 384) {
        int l = idx / (129 * 384);
        int j = idx - l * (129 * 384);
        int r = j / 384;
        int col = j - r * 384;
        const float* Wq_l = Wq + l * 16384;
        const float* Wk_l = Wk + l * 16384;
        const float* Wv_l = Wv + l * 16384;
        const float* ar_l = a_rel + l * 2048;
        const float* mr_l = m_rel + l * 2048;
        float val;
        if (col < 128) {
            val = (r < 128) ? Wq_l[r * 128 + col] : bq[l * 128 + col];
        } else if (col < 256) {
            int cc = col - 128; int h = cc >> 4; int eo = cc & 15;
            float scale = p_rel[l * 8 + h] * 0.25f * 1.4426950408889634f;
            float s = 0.f;
            #pragma unroll
            for (int d = 0; d < 16; ++d) {
                float w = (r < 128) ? Wk_l[r * 128 + h * 16 + d] : bk[l * 128 + h * 16 + d];
                s += w * ar_l[h * 256 + d * 16 + eo];
            }
            val = s * scale;
        } else {
            int cc = col - 256; int h = cc >> 4; int eo = cc & 15;
            float s = 0.f;
            #pragma unroll
            for (int d = 0; d < 16; ++d) {
                float w = (r < 128) ? Wv_l[r * 128 + h * 16 + d] : bv[l * 128 + h * 16 + d];
                s += w * mr_l[h * 256 + d * 16 + eo];
            }
            val = s;
        }
        if (r < 128) BfT[(size_t)l * 49152 + (size_t)col * 128 + r] = f2bf(val);
        else         biasf[l * 384 + col] = val;
    } else if (idx < 2 * 129 * 384 + 2 * 16384) {
        int i = idx - 2 * 129 * 384;
        int l = i >> 14; int j = i & 16383;
        int r = j >> 7, c = j & 127;
        aWT[(size_t)l * 16384 + (size_t)c * 128 + r] = f2bf(aW[(size_t)l * 16384 + r * 128 + c]);
    } else {
        int i = idx - (2 * 129 * 384 + 2 * 16384);
        int c = i >> 7, r = i & 127;
        fcWT[(size_t)c * 128 + r] = f2bf(fcW[(size_t)r * 64 + c]);
    }
}

// ---------------- hierarchical exclusive scan over Hmat (NH elements) -----------
__global__ __launch_bounds__(256) void scan_blocks_kernel(
    const int* __restrict__ in, int* __restrict__ out, int* __restrict__ bsum)
{
    __shared__ int s[256];
    int t = threadIdx.x;
    int i = blockIdx.x * 256 + t;
    int v = (i < NH) ? in[i] : 0;
    s[t] = v;
    __syncthreads();
    #pragma unroll
    for (int off = 1; off < 256; off <<= 1) {
        int u = (t >= off) ? s[t - off] : 0;
        __syncthreads();
        s[t] += u;
        __syncthreads();
    }
    if (i < NH) out[i] = s[t] - v;
    if (t == 255) bsum[blockIdx.x] = s[255];
}

__global__ __launch_bounds__(256) void scan_top_kernel(
    const int* __restrict__ bsum, int* __restrict__ boffs)
{
    __shared__ int s[256];
    int t = threadIdx.x;
    int v = (t < NHB) ? bsum[t] : 0;
    s[t] = v;
    __syncthreads();
    #pragma unroll
    for (int off = 1; off < 256; off <<= 1) {
        int u = (t >= off) ? s[t - off] : 0;
        __syncthreads();
        s[t] += u;
        __syncthreads();
    }
    boffs[t] = s[t] - v;
}

__global__ __launch_bounds__(256) void scan_add_kernel(
    int* __restrict__ out, const int* __restrict__ boffs)
{
    int i = blockIdx.x * 256 + threadIdx.x;
    if (i < NH) out[i] += boffs[blockIdx.x];
}

// ---------------- pass 2: coarse bucketing with LDS cursors ----------------------
__global__ __launch_bounds__(256) void pass2_kernel(
    const int* __restrict__ eidx, const int* __restrict__ O, int* __restrict__ ebuk)
{
    __shared__ int cur[NCO];
    int b = blockIdx.x, t = threadIdx.x;
    if (t < NCO) cur[t] = O[t * P1B + b];
    __syncthreads();
    int base = b * EPB;
    for (int e = base + t; e < base + EPB; e += 256) {
        int s = eidx[e];
        int d = eidx[NE + e];
        int pos = atomicAdd(&cur[d >> 8], 1);
        ebuk[pos] = ((d & 255) << 16) | s;
    }
}

// ---- qkv0 GEMM (blocks 0..624) + CSR pass 3 (blocks 625..781) -------------------
// qb rows: f16 [NN][128].  kvb rows: [k f16 (128) | v bf16 (128)], 512 B.
__global__ __launch_bounds__(256) void qkv0_p3_kernel(
    const float* __restrict__ Af, const unsigned short* __restrict__ BT,
    const float* __restrict__ bias,
    unsigned short* __restrict__ qb, unsigned short* __restrict__ kvb,
    const int* __restrict__ O, const int* __restrict__ ebuk,
    int* __restrict__ deg, int* __restrict__ offs, int* __restrict__ srcSorted)
{
    if (blockIdx.x >= GBLOCKS) {
        // pass 3: fine grouping within one coarse bucket, LDS only
        __shared__ int hist[256], loffs[256], cur[256];
        int c = blockIdx.x - GBLOCKS;
        int t = threadIdx.x;
        int base = O[c * P1B];
        int end = (c < NCO - 1) ? O[(c + 1) * P1B] : NE;
        hist[t] = 0;
        __syncthreads();
        for (int i = base + t; i < end; i += 256)
            atomicAdd(&hist[ebuk[i] >> 16], 1);
        __syncthreads();
        int v = hist[t];
        loffs[t] = v;
        __syncthreads();
        #pragma unroll
        for (int off = 1; off < 256; off <<= 1) {
            int u = (t >= off) ? loffs[t - off] : 0;
            __syncthreads();
            loffs[t] += u;
            __syncthreads();
        }
        int excl = loffs[t] - v;
        int n = c * 256 + t;
        if (n < NN) { deg[n] = v; offs[n] = base + excl; }
        cur[t] = excl;
        __syncthreads();
        for (int i = base + t; i < end; i += 256) {
            int p = ebuk[i];
            int pos = atomicAdd(&cur[p >> 16], 1);
            srcSorted[base + pos] = p & 0xffff;
        }
        return;
    }
    __shared__ unsigned short Bs[64][136];
    int t = threadIdx.x;
    int row0 = blockIdx.x * 64;
    int w = t >> 6;
    int lr = t & 15;
    int quad = (t & 63) >> 4;
    int row = row0 + w * 16 + lr;

    frag8 af[4];
    {
        const float* ap = Af + (size_t)row * 128 + quad * 8;
        #pragma unroll
        for (int kc = 0; kc < 4; ++kc) {
            float4 a0 = *(const float4*)(ap + kc * 32);
            float4 a1 = *(const float4*)(ap + kc * 32 + 4);
            af[kc].u[0] = f2bf(a0.x); af[kc].u[1] = f2bf(a0.y);
            af[kc].u[2] = f2bf(a0.z); af[kc].u[3] = f2bf(a0.w);
            af[kc].u[4] = f2bf(a1.x); af[kc].u[5] = f2bf(a1.y);
            af[kc].u[6] = f2bf(a1.z); af[kc].u[7] = f2bf(a1.w);
        }
    }

    #pragma unroll
    for (int ct = 0; ct < 6; ++ct) {
        if (ct) __syncthreads();
        #pragma unroll
        for (int i = 0; i < 4; ++i) {
            int idx = t + i * 256;
            int r = idx >> 4;
            int c8 = (idx & 15) * 8;
            *(u16x8*)(&Bs[r][c8]) = *(const u16x8*)(BT + (size_t)(ct * 64 + r) * 128 + c8);
        }
        __syncthreads();
        f32x4 acc[4] = {{0.f,0.f,0.f,0.f},{0.f,0.f,0.f,0.f},
                        {0.f,0.f,0.f,0.f},{0.f,0.f,0.f,0.f}};
        #pragma unroll
        for (int kc = 0; kc < 4; ++kc) {
            #pragma unroll
            for (int n4 = 0; n4 < 4; ++n4) {
                short8 bfr = *(const short8*)(&Bs[n4 * 16 + lr][kc * 32 + quad * 8]);
                acc[n4] = __builtin_amdgcn_mfma_f32_16x16x32_bf16(bfr, af[kc].s, acc[n4], 0, 0, 0);
            }
        }
        unsigned short* dst = (ct < 2) ? (qb + (size_t)row * 128 + (ct & 1) * 64)
                                       : (kvb + (size_t)row * 256 + (ct - 2) * 64);
        #pragma unroll
        for (int n4 = 0; n4 < 4; ++n4) {
            int colb = n4 * 16 + quad * 4;
            float4 bv = *(const float4*)(bias + ct * 64 + colb);
            ushort4 o;
            if (ct >= 4) {
                o.x = f2bf(acc[n4][0] + bv.x);
                o.y = f2bf(acc[n4][1] + bv.y);
                o.z = f2bf(acc[n4][2] + bv.z);
                o.w = f2bf(acc[n4][3] + bv.w);
            } else {
                o.x = f2h(acc[n4][0] + bv.x);
                o.y = f2h(acc[n4][1] + bv.y);
                o.z = f2h(acc[n4][2] + bv.z);
                o.w = f2h(acc[n4][3] + bv.w);
            }
            *(ushort4*)(dst + colb) = o;
        }
    }
}

// Fused: out-GEMM (gelu(agg)@aWT + skip -> h) then second GEMM from h (in LDS).
template <int HPFMT, int P2>
__global__ __launch_bounds__(256) void fused_kernel(
    const unsigned short* __restrict__ aggb,
    const unsigned short* __restrict__ aWT, const float* __restrict__ ab,
    const float* __restrict__ skip_p,
    const float* __restrict__ HprevF, const unsigned short* __restrict__ HprevB,
    unsigned short* __restrict__ hb_out,
    const unsigned short* __restrict__ W2T, const float* __restrict__ bias2,
    unsigned short* __restrict__ qb, unsigned short* __restrict__ kvb,
    float* __restrict__ outF)
{
    __shared__ unsigned short As[64][136];
    __shared__ unsigned short Bs[64][136];
    int t = threadIdx.x;
    int row0 = blockIdx.x * 64;
    int w = t >> 6;
    int lr = t & 15;
    int quad = (t & 63) >> 4;
    int row = row0 + w * 16 + lr;

    frag8 agf[4];
    {
        const unsigned short* ap = aggb + (size_t)row * 128 + quad * 8;
        #pragma unroll
        for (int kc = 0; kc < 4; ++kc) {
            u16x8 u = *(const u16x8*)(ap + kc * 32);
            #pragma unroll
            for (int j = 0; j < 8; ++j) agf[kc].u[j] = f2bf(gelu_tanh(bf2f(u[j])));
        }
    }

    float sv = skip_p[0];
    float beta = 1.f / (1.f + expf(-sv));
    float omb = 1.f - beta;

    f32x4 hacc[2][4];
    #pragma unroll
    for (int ct = 0; ct < 2; ++ct) {
        if (ct) __syncthreads();
        #pragma unroll
        for (int i = 0; i < 4; ++i) {
            int idx = t + i * 256;
            int r = idx >> 4;
            int c8 = (idx & 15) * 8;
            *(u16x8*)(&Bs[r][c8]) = *(const u16x8*)(aWT + (size_t)(ct * 64 + r) * 128 + c8);
        }
        __syncthreads();
        #pragma unroll
        for (int n4 = 0; n4 < 4; ++n4) hacc[ct][n4] = (f32x4){0.f,0.f,0.f,0.f};
        #pragma unroll
        for (int kc = 0; kc < 4; ++kc) {
            #pragma unroll
            for (int n4 = 0; n4 < 4; ++n4) {
                short8 bfr = *(const short8*)(&Bs[n4 * 16 + lr][kc * 32 + quad * 8]);
                hacc[ct][n4] = __builtin_amdgcn_mfma_f32_16x16x32_bf16(bfr, agf[kc].s, hacc[ct][n4], 0, 0, 0);
            }
        }
    }

    #pragma unroll
    for (int ct = 0; ct < 2; ++ct) {
        #pragma unroll
        for (int n4 = 0; n4 < 4; ++n4) {
            int colb = ct * 64 + n4 * 16 + quad * 4;
            float4 bv = *(const float4*)(ab + colb);
            float hp[4];
            if (HPFMT == 0) {
                float4 h4 = *(const float4*)(HprevF + (size_t)row * 128 + colb);
                hp[0] = h4.x; hp[1] = h4.y; hp[2] = h4.z; hp[3] = h4.w;
            } else {
                ushort4 h4 = *(const ushort4*)(HprevB + (size_t)row * 128 + colb);
                hp[0] = bf2f(h4.x); hp[1] = bf2f(h4.y); hp[2] = bf2f(h4.z); hp[3] = bf2f(h4.w);
            }
            ushort4 o;
            o.x = f2bf(fmaxf(beta * (hacc[ct][n4][0] + bv.x) + omb * hp[0], 0.f));
            o.y = f2bf(fmaxf(beta * (hacc[ct][n4][1] + bv.y) + omb * hp[1], 0.f));
            o.z = f2bf(fmaxf(beta * (hacc[ct][n4][2] + bv.z) + omb * hp[2], 0.f));
            o.w = f2bf(fmaxf(beta * (hacc[ct][n4][3] + bv.w) + omb * hp[3], 0.f));
            *(ushort4*)(&As[w * 16 + lr][colb]) = o;
            if (P2 == 0) *(ushort4*)(hb_out + (size_t)row * 128 + colb) = o;
        }
    }
    __syncthreads();

    if (P2 == 0) {
        #pragma unroll
        for (int ct = 0; ct < 6; ++ct) {
            if (ct) __syncthreads();
            #pragma unroll
            for (int i = 0; i < 4; ++i) {
                int idx = t + i * 256;
                int r = idx >> 4;
                int c8 = (idx & 15) * 8;
                *(u16x8*)(&Bs[r][c8]) = *(const u16x8*)(W2T + (size_t)(ct * 64 + r) * 128 + c8);
            }
            __syncthreads();
            f32x4 acc[4] = {{0.f,0.f,0.f,0.f},{0.f,0.f,0.f,0.f},
                            {0.f,0.f,0.f,0.f},{0.f,0.f,0.f,0.f}};
            #pragma unroll
            for (int kc = 0; kc < 4; ++kc) {
                short8 afr = *(const short8*)(&As[w * 16 + lr][kc * 32 + quad * 8]);
                #pragma unroll
                for (int n4 = 0; n4 < 4; ++n4) {
                    short8 bfr = *(const short8*)(&Bs[n4 * 16 + lr][kc * 32 + quad * 8]);
                    acc[n4] = __builtin_amdgcn_mfma_f32_16x16x32_bf16(bfr, afr, acc[n4], 0, 0, 0);
                }
            }
            unsigned short* dst = (ct < 2) ? (qb + (size_t)row * 128 + (ct & 1) * 64)
                                           : (kvb + (size_t)row * 256 + (ct - 2) * 64);
            #pragma unroll
            for (int n4 = 0; n4 < 4; ++n4) {
                int colb = n4 * 16 + quad * 4;
                float4 bv = *(const float4*)(bias2 + ct * 64 + colb);
                ushort4 o;
                if (ct >= 4) {
                    o.x = f2bf(acc[n4][0] + bv.x);
                    o.y = f2bf(acc[n4][1] + bv.y);
                    o.z = f2bf(acc[n4][2] + bv.z);
                    o.w = f2bf(acc[n4][3] + bv.w);
                } else {
                    o.x = f2h(acc[n4][0] + bv.x);
                    o.y = f2h(acc[n4][1] + bv.y);
                    o.z = f2h(acc[n4][2] + bv.z);
                    o.w = f2h(acc[n4][3] + bv.w);
                }
                *(ushort4*)(dst + colb) = o;
            }
        }
    } else {
        #pragma unroll
        for (int i = 0; i < 4; ++i) {
            int idx = t + i * 256;
            int r = idx >> 4;
            int c8 = (idx & 15) * 8;
            *(u16x8*)(&Bs[r][c8]) = *(const u16x8*)(W2T + (size_t)r * 128 + c8);
        }
        __syncthreads();
        f32x4 acc[4] = {{0.f,0.f,0.f,0.f},{0.f,0.f,0.f,0.f},
                        {0.f,0.f,0.f,0.f},{0.f,0.f,0.f,0.f}};
        #pragma unroll
        for (int kc = 0; kc < 4; ++kc) {
            short8 afr = *(const short8*)(&As[w * 16 + lr][kc * 32 + quad * 8]);
            #pragma unroll
            for (int n4 = 0; n4 < 4; ++n4) {
                short8 bfr = *(const short8*)(&Bs[n4 * 16 + lr][kc * 32 + quad * 8]);
                acc[n4] = __builtin_amdgcn_mfma_f32_16x16x32_bf16(bfr, afr, acc[n4], 0, 0, 0);
            }
        }
        #pragma unroll
        for (int n4 = 0; n4 < 4; ++n4) {
            int colb = n4 * 16 + quad * 4;
            float4 bv = *(const float4*)(bias2 + colb);
            float4 o;
            o.x = acc[n4][0] + bv.x;
            o.y = acc[n4][1] + bv.y;
            o.z = acc[n4][2] + bv.z;
            o.w = acc[n4][3] + bv.w;
            *(float4*)(outF + (size_t)row * 64 + colb) = o;
        }
    }
}

// ---------------- Fused per-destination softmax + aggregation --------------------
__global__ __launch_bounds__(256) void aggregate_kernel(
    const unsigned short* __restrict__ qb, const unsigned short* __restrict__ kvb,
    const int* __restrict__ deg, const int* __restrict__ offs,
    const int* __restrict__ srcSorted, unsigned short* __restrict__ aggb)
{
    int n = (blockIdx.x * 256 + threadIdx.x) >> 6;
    int lane = threadIdx.x & 63;
    int es = lane >> 3;
    int h = lane & 7;

#if HAS_FDOT2
    h16x2 q2[8];
    {
        const h16x2* qp = (const h16x2*)(qb + (size_t)n * 128 + h * 16);
        #pragma unroll
        for (int j = 0; j < 8; ++j) q2[j] = qp[j];
    }
#else
    float q[16];
    {
        kv8 a, b;
        a.u = *(const u16x8*)(qb + (size_t)n * 128 + h * 16);
        b.u = *(const u16x8*)(qb + (size_t)n * 128 + h * 16 + 8);
        #pragma unroll
        for (int j = 0; j < 8; ++j) { q[j] = (float)a.h[j]; q[8 + j] = (float)b.h[j]; }
    }
#endif
    float acc[16];
    #pragma unroll
    for (int j = 0; j < 16; ++j) acc[j] = 0.f;
    float den = 0.f;

    int start = offs[n];
    int d = deg[n];
    if (d > 0) {
        int ng = (d + 7) >> 3;
        int lastIdx = start + d - 1;

        kv8 ka0, ka1; u16x8 vA0, vA1;
        kv8 kB0, kB1; u16x8 vB0, vB1;
        {
            int i0 = start + es; if (i0 > lastIdx) i0 = lastIdx;
            const unsigned short* p = kvb + (size_t)srcSorted[i0] * 256 + h * 16;
            ka0.u = *(const u16x8*)p;        ka1.u = *(const u16x8*)(p + 8);
            vA0 = *(const u16x8*)(p + 128);  vA1 = *(const u16x8*)(p + 136);
        }
        kB0 = ka0; kB1 = ka1; vB0 = vA0; vB1 = vA1;
        if (ng > 1) {
            int i1 = start + 8 + es; if (i1 > lastIdx) i1 = lastIdx;
            const unsigned short* p = kvb + (size_t)srcSorted[i1] * 256 + h * 16;
            kB0.u = *(const u16x8*)p;        kB1.u = *(const u16x8*)(p + 8);
            vB0 = *(const u16x8*)(p + 128);  vB1 = *(const u16x8*)(p + 136);
        }

        for (int g = 0; g < ng; ++g) {
            kv8 kC0 = ka0, kC1 = ka1; u16x8 vC0 = vA0, vC1 = vA1;
            if (g + 2 < ng) {
                int ni = start + (g + 2) * 8 + es; if (ni > lastIdx) ni = lastIdx;
                const unsigned short* p = kvb + (size_t)srcSorted[ni] * 256 + h * 16;
                kC0.u = *(const u16x8*)p;        kC1.u = *(const u16x8*)(p + 8);
                vC0 = *(const u16x8*)(p + 128);  vC1 = *(const u16x8*)(p + 136);
            }
            float pdot = 0.f;
#if HAS_FDOT2
            #pragma unroll
            for (int j = 0; j < 4; ++j) pdot = __builtin_amdgcn_fdot2(ka0.p[j], q2[j], pdot, false);
            #pragma unroll
            for (int j = 0; j < 4; ++j) pdot = __builtin_amdgcn_fdot2(ka1.p[j], q2[4 + j], pdot, false);
#else
            #pragma unroll
            for (int j = 0; j < 8; ++j) pdot = fmaf((float)ka0.h[j], q[j], pdot);
            #pragma unroll
            for (int j = 0; j < 8; ++j) pdot = fmaf((float)ka1.h[j], q[8 + j], pdot);
#endif
            float ev = (g * 8 + es < d) ? exp2f(pdot) : 0.f;
            den += ev;
            float vf[16];
            unpack8(vA0, vf); unpack8(vA1, vf + 8);
            #pragma unroll
            for (int j = 0; j < 16; ++j) acc[j] = fmaf(vf[j], ev, acc[j]);
            ka0 = kB0; ka1 = kB1; vA0 = vB0; vA1 = vB1;
            kB0 = kC0; kB1 = kC1; vB0 = vC0; vB1 = vC1;
        }
    }
    #pragma unroll
    for (int m = 8; m < 64; m <<= 1) {
        den += __shfl_xor(den, m, 64);
        #pragma unroll
        for (int j = 0; j < 16; ++j) acc[j] += __shfl_xor(acc[j], m, 64);
    }
    if (es == 0) {
        float w = 1.f / (den + 1e-16f);
        u16x8 o0, o1;
        #pragma unroll
        for (int j = 0; j < 8; ++j) {
            o0[j] = f2bf(acc[j] * w);
            o1[j] = f2bf(acc[j + 8] * w);
        }
        *(u16x8*)(aggb + (size_t)n * 128 + h * 16) = o0;
        *(u16x8*)(aggb + (size_t)n * 128 + h * 16 + 8) = o1;
    }
}

extern "C" void kernel_launch(void* const* d_in, const int* in_sizes, int n_in,
                              void* d_out, int out_size, void* d_ws, size_t ws_size,
                              hipStream_t stream) {
    const float* x     = (const float*)d_in[0];
    const int*   eidx  = (const int*)d_in[1];
    const float* Wk    = (const float*)d_in[2];
    const float* bk    = (const float*)d_in[3];
    const float* Wq    = (const float*)d_in[4];
    const float* bq    = (const float*)d_in[5];
    const float* Wv    = (const float*)d_in[6];
    const float* bv    = (const float*)d_in[7];
    const float* a_rel = (const float*)d_in[8];
    const float* m_rel = (const float*)d_in[9];
    const float* p_rel = (const float*)d_in[10];
    const float* skip  = (const float*)d_in[11];
    const float* aW    = (const float*)d_in[12];
    const float* ab    = (const float*)d_in[13];
    const float* fcW   = (const float*)d_in[14];
    const float* fcb   = (const float*)d_in[15];
    float* out = (float*)d_out;

    float* biasf = (float*)d_ws;                              // 2*384
    unsigned short* hb   = (unsigned short*)(biasf + 768);    // NN*128
    unsigned short* qb   = hb + (size_t)NN * 128;             // NN*128 (f16)
    unsigned short* kvb  = qb + (size_t)NN * 128;             // NN*256 ([k f16|v bf16])
    unsigned short* aggb = kvb + (size_t)NN * 256;            // NN*128
    unsigned short* BfT  = aggb + (size_t)NN * 128;           // 2*384*128
    unsigned short* aWT  = BfT + 2 * 384 * 128;               // 2*128*128
    unsigned short* fcWT = aWT + 2 * 128 * 128;               // 64*128
    int* deg       = (int*)(fcWT + 64 * 128);                 // NN
    int* offs      = deg + NN;                                // NN
    int* Hmat      = offs + NN;                               // NH (in-place scanned -> O)
    int* bsum      = Hmat + NH;                               // 256
    int* boffs     = bsum + 256;                              // 256
    int* Oarr      = boffs + 256;                             // NH
    int* ebuk      = Oarr + NH;                               // NE
    int* srcSorted = ebuk + NE;                               // NE

    // weights + coarse hist (one dispatch, disjoint block ranges)
    prep_kernel<<<WBLOCKS + P1B, 256, 0, stream>>>(
        Wq, bq, Wk, bk, a_rel, Wv, bv, m_rel, p_rel, aW, fcW,
        BfT, biasf, aWT, fcWT, eidx, Hmat);
    // exclusive scan Hmat -> Oarr
    scan_blocks_kernel<<<NHB, 256, 0, stream>>>(Hmat, Oarr, bsum);
    scan_top_kernel<<<1, 256, 0, stream>>>(bsum, boffs);
    scan_add_kernel<<<NHB, 256, 0, stream>>>(Oarr, boffs);
    // coarse bucketing
    pass2_kernel<<<P1B, 256, 0, stream>>>(eidx, Oarr, ebuk);

    // ---- layer 0 QKV + CSR pass 3 (co-scheduled) ----
    qkv0_p3_kernel<<<GBLOCKS + NCO, 256, 0, stream>>>(
        x, BfT, biasf, qb, kvb, Oarr, ebuk, deg, offs, srcSorted);
    aggregate_kernel<<<NN / 4, 256, 0, stream>>>(qb, kvb, deg, offs, srcSorted, aggb);

    // ---- fused: out-GEMM(0) -> h0 -> QKV(1) ----
    fused_kernel<0, 0><<<GBLOCKS, 256, 0, stream>>>(
        aggb, aWT, ab, skip, x, nullptr, hb,
        BfT + 49152, biasf + 384, qb, kvb, nullptr);
    aggregate_kernel<<<NN / 4, 256, 0, stream>>>(qb, kvb, deg, offs, srcSorted, aggb);

    // ---- fused: out-GEMM(1) -> h1 (LDS) -> fc ----
    fused_kernel<1, 2><<<GBLOCKS, 256, 0, stream>>>(
        aggb, aWT + 16384, ab + 128, skip + 1, nullptr, hb, nullptr,
        fcWT, fcb, nullptr, nullptr, out);
}